// Round 1
// baseline (416.281 us; speedup 1.0000x reference)
//
#include <hip/hip_runtime.h>
#include <math.h>

// ---------------- problem constants ----------------
#define DD   256
#define NSB  4
#define PPB  4
#define POSB 16
#define LL   2048
#define BB   2
#define NC   8          // time chunks
#define CHK  256        // LL/NC
#define NG   13         // additive groups per batch (cross, 4 banks, 4x pos, 4x ltm), 4 slots each
#define FS   128        // feature row stride (floats)
#define PI_F 3.14159265358979323846f

// feature row offsets (floats)
#define JK_OFF   0
#define JQ_OFF   8
#define KP_OFF   16
#define QP_OFF   48
#define LKP_OFF  80
#define GATE_OFF 112

// workspace layout (float offsets)
#define FEAT_O  0L
#define V_O     524288L                  // BB*LL*FS
#define LV_O    1572864L                 // V_O + BB*LL*DD
#define PPH_O   2621440L                 // LV_O + BB*LL*DD
#define TOT_O   2686976L                 // PPH_O + LL*32
#define CKEY_O  3735552L                 // TOT_O + BB*LL*DD
#define CMEM_O  3736576L                 // CKEY_O + BB*NC*64
#define WGB_O   4162560L                 // CMEM_O + BB*NG*NC*4*2*DD
#define WS_FLOATS 4170752L               // WGB_O + BB*LL*2

__device__ __forceinline__ float sigm(float v){ return 1.0f/(1.0f+expf(-v)); }
__device__ __forceinline__ float gelu_exact(float v){ return 0.5f*v*(1.0f+erff(v*0.70710678118654752f)); }

// ---------------- K0: positional phasor table ----------------
__global__ __launch_bounds__(256) void k0_posph(const float* __restrict__ pf, float* __restrict__ posph){
    int t = blockIdx.x*256 + threadIdx.x;
    if (t >= LL) return;
    #pragma unroll
    for (int j=0;j<POSB;++j){
        // mirror jnp eval order: ((t * f) * 2) * PI
        float ang = (((float)t * pf[j]) * 2.0f) * PI_F;
        float s,c; sincosf(ang,&s,&c);
        posph[t*32+2*j]   = c;
        posph[t*32+2*j+1] = s;
    }
}

// ---------------- K1: per-token features ----------------
__global__ __launch_bounds__(256) void k1_features(
    const float* __restrict__ x,
    const float* __restrict__ kW1, const float* __restrict__ kb1,
    const float* __restrict__ kW2, const float* __restrict__ kb2,
    const float* __restrict__ qW1, const float* __restrict__ qb1,
    const float* __restrict__ qW2, const float* __restrict__ qb2,
    const float* __restrict__ vW,  const float* __restrict__ vb,
    const float* __restrict__ gW1, const float* __restrict__ gb1,
    const float* __restrict__ gW2, const float* __restrict__ gb2,
    const float* __restrict__ lW1, const float* __restrict__ lb1,
    const float* __restrict__ lW2, const float* __restrict__ lb2,
    const float* __restrict__ lvW, const float* __restrict__ lvb,
    float* __restrict__ feat, float* __restrict__ Vbuf, float* __restrict__ lvalbuf)
{
    __shared__ float xs[8][DD];
    __shared__ float hl[8][DD+1];
    __shared__ float ang[8][16];
    __shared__ float gh[8][129];
    int tid = threadIdx.x;
    long base = (long)blockIdx.x * 8;   // flat rows over BB*LL

    for (int tok=0;tok<8;++tok)
        xs[tok][tid] = x[(base+tok)*DD + tid];
    __syncthreads();

    // ---- V and ltm_val projections ----
    {
        float acc[8], acc2[8];
        #pragma unroll
        for (int tok=0;tok<8;++tok){ acc[tok]=vb[tid]; acc2[tok]=lvb[tid]; }
        for (int i=0;i<DD;++i){
            float w = vW[i*DD+tid], w2 = lvW[i*DD+tid];
            #pragma unroll
            for (int tok=0;tok<8;++tok){ acc[tok] += xs[tok][i]*w; acc2[tok] += xs[tok][i]*w2; }
        }
        for (int tok=0;tok<8;++tok){
            Vbuf[(base+tok)*DD+tid]    = acc[tok];
            lvalbuf[(base+tok)*DD+tid] = acc2[tok];
        }
    }

    // ---- k/q/l MLPs (256->256 gelu ->16, tanh*pi -> phasors) ----
    for (int m=0;m<3;++m){
        const float* W1 = (m==0)?kW1:((m==1)?qW1:lW1);
        const float* b1 = (m==0)?kb1:((m==1)?qb1:lb1);
        const float* W2 = (m==0)?kW2:((m==1)?qW2:lW2);
        const float* b2 = (m==0)?kb2:((m==1)?qb2:lb2);
        float h[8];
        #pragma unroll
        for (int tok=0;tok<8;++tok) h[tok]=b1[tid];
        for (int i=0;i<DD;++i){
            float w = W1[i*DD+tid];
            #pragma unroll
            for (int tok=0;tok<8;++tok) h[tok] += xs[tok][i]*w;
        }
        __syncthreads();                   // prior readers of hl/ang done
        for (int tok=0;tok<8;++tok) hl[tok][tid] = gelu_exact(h[tok]);
        __syncthreads();
        if (tid < 128){
            int tok = tid>>4, o = tid&15;
            float acc = b2[o];
            for (int hh=0;hh<DD;++hh) acc += hl[tok][hh]*W2[hh*16+o];
            float a = tanhf(acc)*PI_F;
            ang[tok][o] = a;
            float s,c; sincosf(a,&s,&c);
            int off = (m==0)?KP_OFF:((m==1)?QP_OFF:LKP_OFF);
            feat[(base+tok)*FS + off + 2*o]   = c;
            feat[(base+tok)*FS + off + 2*o+1] = s;
        }
        __syncthreads();
        if (m<2 && tid<32){
            int tok = tid>>2, p = tid&3;
            float a = ang[tok][p]+ang[tok][4+p]+ang[tok][8+p]+ang[tok][12+p];
            float s,c; sincosf(a,&s,&c);
            int off = (m==0)?JK_OFF:JQ_OFF;
            feat[(base+tok)*FS + off + 2*p]   = c;
            feat[(base+tok)*FS + off + 2*p+1] = s;
        }
    }
    __syncthreads();

    // ---- gate MLP (256->128 gelu ->1, sigmoid) ----
    if (tid < 128){
        float hg[8];
        #pragma unroll
        for (int tok=0;tok<8;++tok) hg[tok]=gb1[tid];
        for (int i=0;i<DD;++i){
            float w = gW1[i*128+tid];
            #pragma unroll
            for (int tok=0;tok<8;++tok) hg[tok] += xs[tok][i]*w;
        }
        for (int tok=0;tok<8;++tok) gh[tok][tid] = gelu_exact(hg[tok]);
    }
    __syncthreads();
    if (tid < 8){
        float acc = gb2[0];
        for (int hh=0;hh<128;++hh) acc += gh[tid][hh]*gW2[hh];
        feat[(base+tid)*FS + GATE_OFF] = sigm(acc);
    }
}

// ---------------- G-A: per-chunk key sums (jk 4c + ltm_kp 16c = 40 floats) ----------------
__global__ __launch_bounds__(64) void g_chunksum(const float* __restrict__ feat, float* __restrict__ ckey){
    int b = blockIdx.x / NC, c = blockIdx.x % NC, l = threadIdx.x;
    if (l >= 40) return;
    int off = (l<8) ? (JK_OFF+l) : (LKP_OFF + (l-8));
    long rb = ((long)b*LL + c*CHK)*FS;
    float s = 0.f;
    for (int t=0;t<CHK;++t) s += feat[rb + (long)t*FS + off];
    ckey[(b*NC+c)*64 + l] = s;
}

// ---------------- G-BC: per-chunk gate scan ----------------
__global__ __launch_bounds__(64) void g_scan(
    const float* __restrict__ feat, const float* __restrict__ ckey,
    const float* __restrict__ ss_p, const float* __restrict__ sb_p,
    float* __restrict__ wgbuf)
{
    __shared__ float kl[CHK][40];
    int b = blockIdx.x / NC, c = blockIdx.x % NC, lane = threadIdx.x;
    long rb = ((long)b*LL + c*CHK)*FS;
    for (int idx=lane; idx<CHK*40; idx+=64){
        int t = idx/40, j = idx%40;
        int off = (j<8) ? (JK_OFF+j) : (LKP_OFF + (j-8));
        kl[t][j] = feat[rb + (long)t*FS + off];
    }
    __syncthreads();
    float ss = ss_p[0], sb = sb_p[0];
    bool isjk = (lane<4), isltm = (lane>=16 && lane<32);
    int ci = isjk ? 2*lane : (isltm ? 8+2*(lane-16) : -1);
    float kmr=0.f, kmi=0.f;
    if (ci>=0){
        for (int cc=0; cc<c; ++cc){
            kmr += ckey[(b*NC+cc)*64 + ci];
            kmi += ckey[(b*NC+cc)*64 + ci + 1];
        }
    }
    for (int t=0;t<CHK;++t){
        int tc = c*CHK + t;
        float kr = (ci>=0)? kl[t][ci]   : 0.f;
        float ki = (ci>=0)? kl[t][ci+1] : 0.f;
        // km * conj(k)
        float tr = kmr*kr + kmi*ki;
        float ti = kmi*kr - kmr*ki;
        float sr = tr, si = ti;
        sr += __shfl_xor(sr,1); si += __shfl_xor(si,1);
        sr += __shfl_xor(sr,2); si += __shfl_xor(si,2);
        float pcb = fmaxf((float)tc, 1.0f);
        if (lane==0){
            float res = sqrtf(sr*sr+si*si);
            float fam = fminf(fmaxf(res/(pcb*2.0f),0.f),1.f);
            wgbuf[((long)b*LL+tc)*2] = sigm(ss*(0.5f-fam)+sb);
        }
        sr += __shfl_xor(sr,4); si += __shfl_xor(si,4);
        sr += __shfl_xor(sr,8); si += __shfl_xor(si,8);
        if (lane==16){
            float res = sqrtf(sr*sr+si*si);
            float fam = fminf(fmaxf(res/(pcb*4.0f),0.f),1.f);
            wgbuf[((long)b*LL+tc)*2+1] = sigm(ss*(0.5f-fam)+sb);
        }
        kmr += kr; kmi += ki;
    }
}

// ---------------- M-A: per-chunk memory sums ----------------
__global__ __launch_bounds__(256) void m_chunksum(
    const float* __restrict__ feat, const float* __restrict__ posph,
    const float* __restrict__ wgbuf, const float* __restrict__ Vbuf,
    const float* __restrict__ lvalbuf, float* __restrict__ cmem)
{
    int blk = blockIdx.x;                         // (b*NG+g)*NC + c
    int b = blk/(NG*NC); int r = blk%(NG*NC); int g = r/NC, c = r%NC;
    int d = threadIdx.x;
    __shared__ float kl[CHK][8];
    __shared__ float gl[CHK];
    long frow = ((long)b*LL + c*CHK)*FS;
    for (int idx=threadIdx.x; idx<CHK*8; idx+=256){
        int t = idx>>3, j = idx&7;
        float v;
        if (g==0)       v = feat[frow + (long)t*FS + JK_OFF + j];
        else if (g<5)   v = feat[frow + (long)t*FS + KP_OFF + (g-1)*8 + j];
        else if (g<9)   v = posph[(long)(c*CHK+t)*32 + (g-5)*8 + j];
        else            v = feat[frow + (long)t*FS + LKP_OFF + (g-9)*8 + j];
        kl[t][j] = v;
    }
    for (int t=threadIdx.x; t<CHK; t+=256){
        float gf;
        if (g<5)      gf = wgbuf[((long)b*LL + c*CHK + t)*2];
        else if (g<9) gf = 1.0f;
        else          gf = wgbuf[((long)b*LL + c*CHK + t)*2 + 1];
        gl[t] = gf;
    }
    __syncthreads();
    const float* vsrc = (g>=9)? lvalbuf : Vbuf;
    long vrow = ((long)b*LL + c*CHK)*DD + d;
    float m0r=0,m0i=0,m1r=0,m1i=0,m2r=0,m2i=0,m3r=0,m3i=0;
    for (int t=0;t<CHK;++t){
        float v = vsrc[vrow + (long)t*DD] * gl[t];
        m0r += kl[t][0]*v; m0i += kl[t][1]*v;
        m1r += kl[t][2]*v; m1i += kl[t][3]*v;
        m2r += kl[t][4]*v; m2i += kl[t][5]*v;
        m3r += kl[t][6]*v; m3i += kl[t][7]*v;
    }
    long ob = (long)blk*8*DD + d;   // [blk][slot][reim][DD]
    cmem[ob+0*DD]=m0r; cmem[ob+1*DD]=m0i;
    cmem[ob+2*DD]=m1r; cmem[ob+3*DD]=m1i;
    cmem[ob+4*DD]=m2r; cmem[ob+5*DD]=m2i;
    cmem[ob+6*DD]=m3r; cmem[ob+7*DD]=m3i;
}

// ---------------- M-B: exclusive scan over chunks (in place) ----------------
__global__ __launch_bounds__(256) void m_scan(float* __restrict__ cmem){
    int line = blockIdx.x;            // (b*NG+g)*4 + slot, 104 lines
    int lb = line>>2, slot = line&3, d = threadIdx.x;
    float rr=0.f, ri=0.f;
    for (int c=0;c<NC;++c){
        long a = (((long)(lb*NC + c)*4 + slot)*2)*DD + d;
        float tr = cmem[a], ti = cmem[a+DD];
        cmem[a] = rr; cmem[a+DD] = ri;
        rr += tr; ri += ti;
    }
}

// ---------------- M-C: per-chunk scan + retrieval (atomicAdd into total) ----------------
__global__ __launch_bounds__(256) void m_retrieve(
    const float* __restrict__ feat, const float* __restrict__ posph,
    const float* __restrict__ wgbuf, const float* __restrict__ Vbuf,
    const float* __restrict__ lvalbuf, const float* __restrict__ cmem,
    const float* __restrict__ set_w, const float* __restrict__ pos_w,
    const float* __restrict__ ltm_w, float* __restrict__ total)
{
    int blk = blockIdx.x;
    int b = blk/(NG*NC); int r = blk%(NG*NC); int g = r/NC, c = r%NC;
    int d = threadIdx.x;
    __shared__ float kl[CHK][8];
    __shared__ float ql[CHK][8];
    __shared__ float gl[CHK];
    __shared__ float sl[CHK];
    long frow = ((long)b*LL + c*CHK)*FS;
    for (int idx=threadIdx.x; idx<CHK*8; idx+=256){
        int t = idx>>3, j = idx&7;
        float kv, qv;
        if (g==0){
            kv = feat[frow + (long)t*FS + JK_OFF + j];
            qv = feat[frow + (long)t*FS + JQ_OFF + j];
        } else if (g<5){
            kv = feat[frow + (long)t*FS + KP_OFF + (g-1)*8 + j];
            qv = feat[frow + (long)t*FS + QP_OFF + (g-1)*8 + j];
        } else if (g<9){
            kv = qv = posph[(long)(c*CHK+t)*32 + (g-5)*8 + j];
        } else {
            kv = qv = feat[frow + (long)t*FS + LKP_OFF + (g-9)*8 + j];
        }
        kl[t][j] = kv; ql[t][j] = qv;
    }
    for (int t=threadIdx.x; t<CHK; t+=256){
        int tc = c*CHK + t;
        float gate = feat[frow + (long)t*FS + GATE_OFF];
        float gf, sc;
        if (g<5){
            gf = wgbuf[((long)b*LL+tc)*2];
            if (g==0) sc = gate*0.2f;
            else {
                float w0=expf(set_w[0]),w1=expf(set_w[1]),w2=expf(set_w[2]),w3=expf(set_w[3]);
                float den = w0+w1+w2+w3;
                float wsv = (g==1)?w0:((g==2)?w1:((g==3)?w2:w3));
                sc = gate*0.2f*wsv/den;
            }
        } else if (g<9){
            gf = 1.0f;
            sc = (1.0f-gate)*sigm(pos_w[0]);
        } else {
            gf = wgbuf[((long)b*LL+tc)*2+1];
            sc = sigm(ltm_w[0]) * rsqrtf((float)(tc+1)*16.0f);
        }
        gl[t]=gf; sl[t]=sc;
    }
    __syncthreads();
    const float* vsrc = (g>=9)? lvalbuf : Vbuf;
    long vrow = ((long)b*LL + c*CHK)*DD + d;
    long cb = (long)blk*8*DD + d;
    float m0r=cmem[cb+0*DD], m0i=cmem[cb+1*DD];
    float m1r=cmem[cb+2*DD], m1i=cmem[cb+3*DD];
    float m2r=cmem[cb+4*DD], m2i=cmem[cb+5*DD];
    float m3r=cmem[cb+6*DD], m3i=cmem[cb+7*DD];
    float* tp = total + ((long)b*LL + c*CHK)*DD + d;
    for (int t=0;t<CHK;++t){
        float v = vsrc[vrow + (long)t*DD] * gl[t];
        m0r += kl[t][0]*v; m0i += kl[t][1]*v;
        m1r += kl[t][2]*v; m1i += kl[t][3]*v;
        m2r += kl[t][4]*v; m2i += kl[t][5]*v;
        m3r += kl[t][6]*v; m3i += kl[t][7]*v;
        float rs = m0r*ql[t][0] + m0i*ql[t][1]
                 + m1r*ql[t][2] + m1i*ql[t][3]
                 + m2r*ql[t][4] + m2i*ql[t][5]
                 + m3r*ql[t][6] + m3i*ql[t][7];
        atomicAdd(tp + (long)t*DD, rs*sl[t]);
    }
}

// ---------------- K4: normalize + LN + output projection + residual ----------------
__global__ __launch_bounds__(256) void k4_out(
    const float* __restrict__ x, const float* __restrict__ total,
    const float* __restrict__ ln_g, const float* __restrict__ ln_b,
    const float* __restrict__ oW,  const float* __restrict__ obv,
    float* __restrict__ out)
{
    __shared__ float tn[8][DD];
    int tid = threadIdx.x;
    long base = (long)blockIdx.x*8;
    int wave = tid>>6, lane = tid&63;
    for (int wtok=0; wtok<2; ++wtok){
        int tok = wave*2 + wtok;
        long row = base + tok;
        int tc = (int)(row % LL);
        float inv = rsqrtf((float)(tc+1)*4.0f);
        float4 tv4 = ((const float4*)(total + row*DD))[lane];
        float vals[4] = {tv4.x*inv, tv4.y*inv, tv4.z*inv, tv4.w*inv};
        float s=0.f, s2=0.f;
        #pragma unroll
        for (int k=0;k<4;++k){ s += vals[k]; s2 += vals[k]*vals[k]; }
        for (int o=1;o<64;o<<=1){ s += __shfl_xor(s,o); s2 += __shfl_xor(s2,o); }
        float mu = s/256.f, var = s2/256.f - mu*mu;
        float rstd = rsqrtf(var + 1e-5f);
        float4 w;
        w.x = (vals[0]-mu)*rstd*ln_g[lane*4+0] + ln_b[lane*4+0];
        w.y = (vals[1]-mu)*rstd*ln_g[lane*4+1] + ln_b[lane*4+1];
        w.z = (vals[2]-mu)*rstd*ln_g[lane*4+2] + ln_b[lane*4+2];
        w.w = (vals[3]-mu)*rstd*ln_g[lane*4+3] + ln_b[lane*4+3];
        ((float4*)&tn[tok][0])[lane] = w;
    }
    __syncthreads();
    float acc[8];
    #pragma unroll
    for (int tok=0;tok<8;++tok) acc[tok]=obv[tid];
    for (int i=0;i<DD;++i){
        float w = oW[i*DD+tid];
        #pragma unroll
        for (int tok=0;tok<8;++tok) acc[tok] += tn[tok][i]*w;
    }
    for (int tok=0;tok<8;++tok){
        long row = base+tok;
        out[row*DD+tid] = x[row*DD+tid] + acc[tok];
    }
}

// ---------------- launch ----------------
extern "C" void kernel_launch(void* const* d_in, const int* in_sizes, int n_in,
                              void* d_out, int out_size, void* d_ws, size_t ws_size,
                              hipStream_t stream)
{
    const float* x    = (const float*)d_in[0];
    const float* kW1  = (const float*)d_in[1];
    const float* kb1  = (const float*)d_in[2];
    const float* kW2  = (const float*)d_in[3];
    const float* kb2  = (const float*)d_in[4];
    const float* qW1  = (const float*)d_in[5];
    const float* qb1  = (const float*)d_in[6];
    const float* qW2  = (const float*)d_in[7];
    const float* qb2  = (const float*)d_in[8];
    const float* vW   = (const float*)d_in[9];
    const float* vb   = (const float*)d_in[10];
    const float* ln_g = (const float*)d_in[11];
    const float* ln_b = (const float*)d_in[12];
    const float* oW   = (const float*)d_in[13];
    const float* ob   = (const float*)d_in[14];
    const float* set_w= (const float*)d_in[15];
    const float* pf   = (const float*)d_in[16];
    const float* pw   = (const float*)d_in[17];
    const float* gW1  = (const float*)d_in[18];
    const float* gb1  = (const float*)d_in[19];
    const float* gW2  = (const float*)d_in[20];
    const float* gb2  = (const float*)d_in[21];
    const float* lW1  = (const float*)d_in[22];
    const float* lb1  = (const float*)d_in[23];
    const float* lW2  = (const float*)d_in[24];
    const float* lb2  = (const float*)d_in[25];
    const float* lvW  = (const float*)d_in[26];
    const float* lvb  = (const float*)d_in[27];
    const float* ss   = (const float*)d_in[28];
    const float* sb   = (const float*)d_in[29];
    const float* lw   = (const float*)d_in[30];
    float* out = (float*)d_out;

    float* ws    = (float*)d_ws;
    float* feat  = ws + FEAT_O;
    float* Vbuf  = ws + V_O;
    float* lval  = ws + LV_O;
    float* posph = ws + PPH_O;
    float* total = ws + TOT_O;
    float* ckey  = ws + CKEY_O;
    float* cmem  = ws + CMEM_O;
    float* wgbuf = ws + WGB_O;

    (void)in_sizes; (void)n_in; (void)out_size; (void)ws_size;

    hipMemsetAsync(total, 0, (size_t)BB*LL*DD*sizeof(float), stream);

    k0_posph   <<<LL/256, 256, 0, stream>>>(pf, posph);
    k1_features<<<BB*LL/8, 256, 0, stream>>>(x, kW1,kb1,kW2,kb2, qW1,qb1,qW2,qb2,
                                             vW,vb, gW1,gb1,gW2,gb2, lW1,lb1,lW2,lb2,
                                             lvW,lvb, feat, Vbuf, lval);
    g_chunksum <<<BB*NC, 64, 0, stream>>>(feat, ckey);
    g_scan     <<<BB*NC, 64, 0, stream>>>(feat, ckey, ss, sb, wgbuf);
    m_chunksum <<<BB*NG*NC, 256, 0, stream>>>(feat, posph, wgbuf, Vbuf, lval, cmem);
    m_scan     <<<BB*NG*4, 256, 0, stream>>>(cmem);
    m_retrieve <<<BB*NG*NC, 256, 0, stream>>>(feat, posph, wgbuf, Vbuf, lval, cmem,
                                              set_w, pw, lw, total);
    k4_out     <<<BB*LL/8, 256, 0, stream>>>(x, total, ln_g, ln_b, oW, ob, out);
}

// Round 2
// 299.430 us; speedup vs baseline: 1.3902x; 1.3902x over previous
//
#include <hip/hip_runtime.h>
#include <math.h>

// ---------------- problem constants ----------------
#define DD   256
#define NSB  4
#define PPB  4
#define POSB 16
#define LL   2048
#define BB   2
#define NC   8          // time chunks
#define CHK  256        // LL/NC
#define NG   13         // additive groups per batch (cross, 4 banks, 4x pos, 4x ltm), 4 slots each
#define FS   128        // feature row stride (floats)
#define PI_F 3.14159265358979323846f

// feature row offsets (floats)
#define JK_OFF   0
#define JQ_OFF   8
#define KP_OFF   16
#define QP_OFF   48
#define LKP_OFF  80
#define GATE_OFF 112

// workspace layout (float offsets)
#define FEAT_O  0L
#define V_O     524288L                  // BB*LL*FS
#define LV_O    1572864L                 // V_O + BB*LL*DD
#define PPH_O   2621440L                 // LV_O + BB*LL*DD
#define TOT_O   2686976L                 // PPH_O + LL*32
#define CMEM_O  3735552L                 // TOT_O + BB*LL*DD
#define KM_O    CMEM_O                   // km aliases cmem (km dead before m_chunksum runs)
#define WGB_O   4161536L                 // CMEM_O + BB*NG*NC*4*2*DD
#define WS_FLOATS 4169728L               // WGB_O + BB*LL*2

__device__ __forceinline__ float sigm(float v){ return 1.0f/(1.0f+expf(-v)); }
__device__ __forceinline__ float gelu_exact(float v){ return 0.5f*v*(1.0f+erff(v*0.70710678118654752f)); }

// ---------------- K0: positional phasor table ----------------
__global__ __launch_bounds__(256) void k0_posph(const float* __restrict__ pf, float* __restrict__ posph){
    int t = blockIdx.x*256 + threadIdx.x;
    if (t >= LL) return;
    #pragma unroll
    for (int j=0;j<POSB;++j){
        float ang = (((float)t * pf[j]) * 2.0f) * PI_F;
        float s,c; sincosf(ang,&s,&c);
        posph[t*32+2*j]   = c;
        posph[t*32+2*j+1] = s;
    }
}

// ---------------- K1: per-token features (4 tokens/block for occupancy) ----------------
#define TOKS 4
__global__ __launch_bounds__(256) void k1_features(
    const float* __restrict__ x,
    const float* __restrict__ kW1, const float* __restrict__ kb1,
    const float* __restrict__ kW2, const float* __restrict__ kb2,
    const float* __restrict__ qW1, const float* __restrict__ qb1,
    const float* __restrict__ qW2, const float* __restrict__ qb2,
    const float* __restrict__ vW,  const float* __restrict__ vb,
    const float* __restrict__ gW1, const float* __restrict__ gb1,
    const float* __restrict__ gW2, const float* __restrict__ gb2,
    const float* __restrict__ lW1, const float* __restrict__ lb1,
    const float* __restrict__ lW2, const float* __restrict__ lb2,
    const float* __restrict__ lvW, const float* __restrict__ lvb,
    float* __restrict__ feat, float* __restrict__ Vbuf, float* __restrict__ lvalbuf)
{
    __shared__ float xs[TOKS][DD];
    __shared__ float hl[TOKS][DD+1];
    __shared__ float ang[TOKS][16];
    __shared__ float gh[TOKS][129];
    int tid = threadIdx.x;
    long base = (long)blockIdx.x * TOKS;   // flat rows over BB*LL

    #pragma unroll
    for (int tok=0;tok<TOKS;++tok)
        xs[tok][tid] = x[(base+tok)*DD + tid];
    __syncthreads();

    // ---- V and ltm_val projections ----
    {
        float acc[TOKS], acc2[TOKS];
        #pragma unroll
        for (int tok=0;tok<TOKS;++tok){ acc[tok]=vb[tid]; acc2[tok]=lvb[tid]; }
        #pragma unroll 4
        for (int i=0;i<DD;++i){
            float w = vW[i*DD+tid], w2 = lvW[i*DD+tid];
            #pragma unroll
            for (int tok=0;tok<TOKS;++tok){ acc[tok] += xs[tok][i]*w; acc2[tok] += xs[tok][i]*w2; }
        }
        #pragma unroll
        for (int tok=0;tok<TOKS;++tok){
            Vbuf[(base+tok)*DD+tid]    = acc[tok];
            lvalbuf[(base+tok)*DD+tid] = acc2[tok];
        }
    }

    // ---- k/q/l MLPs (256->256 gelu ->16, tanh*pi -> phasors) ----
    for (int m=0;m<3;++m){
        const float* W1 = (m==0)?kW1:((m==1)?qW1:lW1);
        const float* b1 = (m==0)?kb1:((m==1)?qb1:lb1);
        const float* W2 = (m==0)?kW2:((m==1)?qW2:lW2);
        const float* b2 = (m==0)?kb2:((m==1)?qb2:lb2);
        float h[TOKS];
        #pragma unroll
        for (int tok=0;tok<TOKS;++tok) h[tok]=b1[tid];
        #pragma unroll 4
        for (int i=0;i<DD;++i){
            float w = W1[i*DD+tid];
            #pragma unroll
            for (int tok=0;tok<TOKS;++tok) h[tok] += xs[tok][i]*w;
        }
        __syncthreads();                   // prior readers of hl/ang done
        #pragma unroll
        for (int tok=0;tok<TOKS;++tok) hl[tok][tid] = gelu_exact(h[tok]);
        __syncthreads();
        if (tid < TOKS*16){
            int tok = tid>>4, o = tid&15;
            float acc = b2[o];
            #pragma unroll 4
            for (int hh=0;hh<DD;++hh) acc += hl[tok][hh]*W2[hh*16+o];
            float a = tanhf(acc)*PI_F;
            ang[tok][o] = a;
            float s,c; sincosf(a,&s,&c);
            int off = (m==0)?KP_OFF:((m==1)?QP_OFF:LKP_OFF);
            feat[(base+tok)*FS + off + 2*o]   = c;
            feat[(base+tok)*FS + off + 2*o+1] = s;
        }
        __syncthreads();
        if (m<2 && tid<TOKS*4){
            int tok = tid>>2, p = tid&3;
            float a = ang[tok][p]+ang[tok][4+p]+ang[tok][8+p]+ang[tok][12+p];
            float s,c; sincosf(a,&s,&c);
            int off = (m==0)?JK_OFF:JQ_OFF;
            feat[(base+tok)*FS + off + 2*p]   = c;
            feat[(base+tok)*FS + off + 2*p+1] = s;
        }
    }
    __syncthreads();

    // ---- gate MLP (256->128 gelu ->1, sigmoid) ----
    if (tid < 128){
        float hg[TOKS];
        #pragma unroll
        for (int tok=0;tok<TOKS;++tok) hg[tok]=gb1[tid];
        #pragma unroll 4
        for (int i=0;i<DD;++i){
            float w = gW1[i*128+tid];
            #pragma unroll
            for (int tok=0;tok<TOKS;++tok) hg[tok] += xs[tok][i]*w;
        }
        #pragma unroll
        for (int tok=0;tok<TOKS;++tok) gh[tok][tid] = gelu_exact(hg[tok]);
    }
    __syncthreads();
    if (tid < TOKS){
        float acc = gb2[0];
        #pragma unroll 4
        for (int hh=0;hh<128;++hh) acc += gh[tid][hh]*gW2[hh];
        feat[(base+tid)*FS + GATE_OFF] = sigm(acc);
    }
}

// ---------------- G-A: parallel exclusive prefix of 40 key channels ----------------
// grid = BB*40 blocks, 256 threads; each thread owns 8 tokens
__global__ __launch_bounds__(256) void g_prefix(const float* __restrict__ feat, float* __restrict__ km){
    int b = blockIdx.x / 40, ch = blockIdx.x % 40;
    int off = (ch<8) ? (JK_OFF+ch) : (LKP_OFF + (ch-8));
    int tid = threadIdx.x;
    long rb = (long)b*LL*FS;
    float v[8]; float s = 0.f;
    #pragma unroll
    for (int u=0;u<8;++u){
        v[u] = feat[rb + (long)(tid*8+u)*FS + off];
        s += v[u];
    }
    // block-wide exclusive scan of per-thread sums
    int lane = tid & 63, w = tid >> 6;
    float xsc = s;
    #pragma unroll
    for (int o=1;o<64;o<<=1){ float y = __shfl_up(xsc,o); if (lane>=o) xsc += y; }
    __shared__ float wsum[4];
    if (lane==63) wsum[w] = xsc;
    __syncthreads();
    float woff = 0.f;
    for (int i=0;i<w;++i) woff += wsum[i];
    float run = (xsc - s) + woff;       // exclusive prefix for this thread's first token
    #pragma unroll
    for (int u=0;u<8;++u){
        km[((long)b*LL + tid*8+u)*40 + ch] = run;
        run += v[u];
    }
}

// ---------------- G-B: per-token familiarity + write gates (fully parallel) ----------------
__global__ __launch_bounds__(256) void g_fam(
    const float* __restrict__ feat, const float* __restrict__ km,
    const float* __restrict__ ss_p, const float* __restrict__ sb_p,
    float* __restrict__ wgbuf)
{
    int t = blockIdx.x*256 + threadIdx.x;     // global token over BB*LL
    if (t >= BB*LL) return;
    int tc = t % LL;
    float ss = ss_p[0], sb = sb_p[0];
    long frow = (long)t*FS;
    const float* kmrow = km + (long)t*40;
    float pcb = fmaxf((float)tc, 1.0f);

    float sr=0.f, si=0.f;
    #pragma unroll
    for (int p=0;p<4;++p){
        float kr = feat[frow+JK_OFF+2*p], ki = feat[frow+JK_OFF+2*p+1];
        float kmr = kmrow[2*p], kmi = kmrow[2*p+1];
        sr += kmr*kr + kmi*ki;
        si += kmi*kr - kmr*ki;
    }
    float res = sqrtf(sr*sr+si*si);
    float fam = fminf(fmaxf(res/(pcb*2.0f),0.f),1.f);
    wgbuf[(long)t*2] = sigm(ss*(0.5f-fam)+sb);

    sr=0.f; si=0.f;
    #pragma unroll
    for (int p=0;p<16;++p){
        float kr = feat[frow+LKP_OFF+2*p], ki = feat[frow+LKP_OFF+2*p+1];
        float kmr = kmrow[8+2*p], kmi = kmrow[8+2*p+1];
        sr += kmr*kr + kmi*ki;
        si += kmi*kr - kmr*ki;
    }
    float res2 = sqrtf(sr*sr+si*si);
    float fam2 = fminf(fmaxf(res2/(pcb*4.0f),0.f),1.f);
    wgbuf[(long)t*2+1] = sigm(ss*(0.5f-fam2)+sb);
}

// ---------------- M-A: per-chunk memory sums ----------------
__global__ __launch_bounds__(256) void m_chunksum(
    const float* __restrict__ feat, const float* __restrict__ posph,
    const float* __restrict__ wgbuf, const float* __restrict__ Vbuf,
    const float* __restrict__ lvalbuf, float* __restrict__ cmem)
{
    int blk = blockIdx.x;                         // (b*NG+g)*NC + c
    int b = blk/(NG*NC); int r = blk%(NG*NC); int g = r/NC, c = r%NC;
    int d = threadIdx.x;
    __shared__ float kl[CHK][8];
    __shared__ float gl[CHK];
    long frow = ((long)b*LL + c*CHK)*FS;
    for (int idx=threadIdx.x; idx<CHK*8; idx+=256){
        int t = idx>>3, j = idx&7;
        float v;
        if (g==0)       v = feat[frow + (long)t*FS + JK_OFF + j];
        else if (g<5)   v = feat[frow + (long)t*FS + KP_OFF + (g-1)*8 + j];
        else if (g<9)   v = posph[(long)(c*CHK+t)*32 + (g-5)*8 + j];
        else            v = feat[frow + (long)t*FS + LKP_OFF + (g-9)*8 + j];
        kl[t][j] = v;
    }
    for (int t=threadIdx.x; t<CHK; t+=256){
        float gf;
        if (g<5)      gf = wgbuf[((long)b*LL + c*CHK + t)*2];
        else if (g<9) gf = 1.0f;
        else          gf = wgbuf[((long)b*LL + c*CHK + t)*2 + 1];
        gl[t] = gf;
    }
    __syncthreads();
    const float* vsrc = (g>=9)? lvalbuf : Vbuf;
    long vrow = ((long)b*LL + c*CHK)*DD + d;
    float m0r=0,m0i=0,m1r=0,m1i=0,m2r=0,m2i=0,m3r=0,m3i=0;
    for (int t=0;t<CHK;++t){
        float v = vsrc[vrow + (long)t*DD] * gl[t];
        m0r += kl[t][0]*v; m0i += kl[t][1]*v;
        m1r += kl[t][2]*v; m1i += kl[t][3]*v;
        m2r += kl[t][4]*v; m2i += kl[t][5]*v;
        m3r += kl[t][6]*v; m3i += kl[t][7]*v;
    }
    long ob = (long)blk*8*DD + d;   // [blk][slot][reim][DD]
    cmem[ob+0*DD]=m0r; cmem[ob+1*DD]=m0i;
    cmem[ob+2*DD]=m1r; cmem[ob+3*DD]=m1i;
    cmem[ob+4*DD]=m2r; cmem[ob+5*DD]=m2i;
    cmem[ob+6*DD]=m3r; cmem[ob+7*DD]=m3i;
}

// ---------------- M-B: exclusive scan over chunks (in place) ----------------
__global__ __launch_bounds__(256) void m_scan(float* __restrict__ cmem){
    int line = blockIdx.x;            // (b*NG+g)*4 + slot, 104 lines
    int lb = line>>2, slot = line&3, d = threadIdx.x;
    float rr=0.f, ri=0.f;
    for (int c=0;c<NC;++c){
        long a = (((long)(lb*NC + c)*4 + slot)*2)*DD + d;
        float tr = cmem[a], ti = cmem[a+DD];
        cmem[a] = rr; cmem[a+DD] = ri;
        rr += tr; ri += ti;
    }
}

// ---------------- M-C: per-chunk scan + retrieval (atomicAdd into total) ----------------
__global__ __launch_bounds__(256) void m_retrieve(
    const float* __restrict__ feat, const float* __restrict__ posph,
    const float* __restrict__ wgbuf, const float* __restrict__ Vbuf,
    const float* __restrict__ lvalbuf, const float* __restrict__ cmem,
    const float* __restrict__ set_w, const float* __restrict__ pos_w,
    const float* __restrict__ ltm_w, float* __restrict__ total)
{
    int blk = blockIdx.x;
    int b = blk/(NG*NC); int r = blk%(NG*NC); int g = r/NC, c = r%NC;
    int d = threadIdx.x;
    __shared__ float kl[CHK][8];
    __shared__ float ql[CHK][8];
    __shared__ float gl[CHK];
    __shared__ float sl[CHK];
    long frow = ((long)b*LL + c*CHK)*FS;
    for (int idx=threadIdx.x; idx<CHK*8; idx+=256){
        int t = idx>>3, j = idx&7;
        float kv, qv;
        if (g==0){
            kv = feat[frow + (long)t*FS + JK_OFF + j];
            qv = feat[frow + (long)t*FS + JQ_OFF + j];
        } else if (g<5){
            kv = feat[frow + (long)t*FS + KP_OFF + (g-1)*8 + j];
            qv = feat[frow + (long)t*FS + QP_OFF + (g-1)*8 + j];
        } else if (g<9){
            kv = qv = posph[(long)(c*CHK+t)*32 + (g-5)*8 + j];
        } else {
            kv = qv = feat[frow + (long)t*FS + LKP_OFF + (g-9)*8 + j];
        }
        kl[t][j] = kv; ql[t][j] = qv;
    }
    for (int t=threadIdx.x; t<CHK; t+=256){
        int tc = c*CHK + t;
        float gate = feat[frow + (long)t*FS + GATE_OFF];
        float gf, sc;
        if (g<5){
            gf = wgbuf[((long)b*LL+tc)*2];
            if (g==0) sc = gate*0.2f;
            else {
                float w0=expf(set_w[0]),w1=expf(set_w[1]),w2=expf(set_w[2]),w3=expf(set_w[3]);
                float den = w0+w1+w2+w3;
                float wsv = (g==1)?w0:((g==2)?w1:((g==3)?w2:w3));
                sc = gate*0.2f*wsv/den;
            }
        } else if (g<9){
            gf = 1.0f;
            sc = (1.0f-gate)*sigm(pos_w[0]);
        } else {
            gf = wgbuf[((long)b*LL+tc)*2+1];
            sc = sigm(ltm_w[0]) * rsqrtf((float)(tc+1)*16.0f);
        }
        gl[t]=gf; sl[t]=sc;
    }
    __syncthreads();
    const float* vsrc = (g>=9)? lvalbuf : Vbuf;
    long vrow = ((long)b*LL + c*CHK)*DD + d;
    long cb = (long)blk*8*DD + d;
    float m0r=cmem[cb+0*DD], m0i=cmem[cb+1*DD];
    float m1r=cmem[cb+2*DD], m1i=cmem[cb+3*DD];
    float m2r=cmem[cb+4*DD], m2i=cmem[cb+5*DD];
    float m3r=cmem[cb+6*DD], m3i=cmem[cb+7*DD];
    float* tp = total + ((long)b*LL + c*CHK)*DD + d;
    for (int t=0;t<CHK;++t){
        float v = vsrc[vrow + (long)t*DD] * gl[t];
        m0r += kl[t][0]*v; m0i += kl[t][1]*v;
        m1r += kl[t][2]*v; m1i += kl[t][3]*v;
        m2r += kl[t][4]*v; m2i += kl[t][5]*v;
        m3r += kl[t][6]*v; m3i += kl[t][7]*v;
        float rs = m0r*ql[t][0] + m0i*ql[t][1]
                 + m1r*ql[t][2] + m1i*ql[t][3]
                 + m2r*ql[t][4] + m2i*ql[t][5]
                 + m3r*ql[t][6] + m3i*ql[t][7];
        atomicAdd(tp + (long)t*DD, rs*sl[t]);
    }
}

// ---------------- K4: normalize + LN + output projection + residual ----------------
__global__ __launch_bounds__(256) void k4_out(
    const float* __restrict__ x, const float* __restrict__ total,
    const float* __restrict__ ln_g, const float* __restrict__ ln_b,
    const float* __restrict__ oW,  const float* __restrict__ obv,
    float* __restrict__ out)
{
    __shared__ float tn[8][DD];
    int tid = threadIdx.x;
    long base = (long)blockIdx.x*8;
    int wave = tid>>6, lane = tid&63;
    for (int wtok=0; wtok<2; ++wtok){
        int tok = wave*2 + wtok;
        long row = base + tok;
        int tc = (int)(row % LL);
        float inv = rsqrtf((float)(tc+1)*4.0f);
        float4 tv4 = ((const float4*)(total + row*DD))[lane];
        float vals[4] = {tv4.x*inv, tv4.y*inv, tv4.z*inv, tv4.w*inv};
        float s=0.f, s2=0.f;
        #pragma unroll
        for (int k=0;k<4;++k){ s += vals[k]; s2 += vals[k]*vals[k]; }
        for (int o=1;o<64;o<<=1){ s += __shfl_xor(s,o); s2 += __shfl_xor(s2,o); }
        float mu = s/256.f, var = s2/256.f - mu*mu;
        float rstd = rsqrtf(var + 1e-5f);
        float4 w;
        w.x = (vals[0]-mu)*rstd*ln_g[lane*4+0] + ln_b[lane*4+0];
        w.y = (vals[1]-mu)*rstd*ln_g[lane*4+1] + ln_b[lane*4+1];
        w.z = (vals[2]-mu)*rstd*ln_g[lane*4+2] + ln_b[lane*4+2];
        w.w = (vals[3]-mu)*rstd*ln_g[lane*4+3] + ln_b[lane*4+3];
        ((float4*)&tn[tok][0])[lane] = w;
    }
    __syncthreads();
    float acc[8];
    #pragma unroll
    for (int tok=0;tok<8;++tok) acc[tok]=obv[tid];
    #pragma unroll 4
    for (int i=0;i<DD;++i){
        float w = oW[i*DD+tid];
        #pragma unroll
        for (int tok=0;tok<8;++tok) acc[tok] += tn[tok][i]*w;
    }
    for (int tok=0;tok<8;++tok){
        long row = base+tok;
        out[row*DD+tid] = x[row*DD+tid] + acc[tok];
    }
}

// ---------------- launch ----------------
extern "C" void kernel_launch(void* const* d_in, const int* in_sizes, int n_in,
                              void* d_out, int out_size, void* d_ws, size_t ws_size,
                              hipStream_t stream)
{
    const float* x    = (const float*)d_in[0];
    const float* kW1  = (const float*)d_in[1];
    const float* kb1  = (const float*)d_in[2];
    const float* kW2  = (const float*)d_in[3];
    const float* kb2  = (const float*)d_in[4];
    const float* qW1  = (const float*)d_in[5];
    const float* qb1  = (const float*)d_in[6];
    const float* qW2  = (const float*)d_in[7];
    const float* qb2  = (const float*)d_in[8];
    const float* vW   = (const float*)d_in[9];
    const float* vb   = (const float*)d_in[10];
    const float* ln_g = (const float*)d_in[11];
    const float* ln_b = (const float*)d_in[12];
    const float* oW   = (const float*)d_in[13];
    const float* ob   = (const float*)d_in[14];
    const float* set_w= (const float*)d_in[15];
    const float* pf   = (const float*)d_in[16];
    const float* pw   = (const float*)d_in[17];
    const float* gW1  = (const float*)d_in[18];
    const float* gb1  = (const float*)d_in[19];
    const float* gW2  = (const float*)d_in[20];
    const float* gb2  = (const float*)d_in[21];
    const float* lW1  = (const float*)d_in[22];
    const float* lb1  = (const float*)d_in[23];
    const float* lW2  = (const float*)d_in[24];
    const float* lb2  = (const float*)d_in[25];
    const float* lvW  = (const float*)d_in[26];
    const float* lvb  = (const float*)d_in[27];
    const float* ss   = (const float*)d_in[28];
    const float* sb   = (const float*)d_in[29];
    const float* lw   = (const float*)d_in[30];
    float* out = (float*)d_out;

    float* ws    = (float*)d_ws;
    float* feat  = ws + FEAT_O;
    float* Vbuf  = ws + V_O;
    float* lval  = ws + LV_O;
    float* posph = ws + PPH_O;
    float* total = ws + TOT_O;
    float* cmem  = ws + CMEM_O;
    float* km    = ws + KM_O;
    float* wgbuf = ws + WGB_O;

    (void)in_sizes; (void)n_in; (void)out_size; (void)ws_size;

    hipMemsetAsync(total, 0, (size_t)BB*LL*DD*sizeof(float), stream);

    k0_posph   <<<LL/256, 256, 0, stream>>>(pf, posph);
    k1_features<<<BB*LL/TOKS, 256, 0, stream>>>(x, kW1,kb1,kW2,kb2, qW1,qb1,qW2,qb2,
                                             vW,vb, gW1,gb1,gW2,gb2, lW1,lb1,lW2,lb2,
                                             lvW,lvb, feat, Vbuf, lval);
    g_prefix   <<<BB*40, 256, 0, stream>>>(feat, km);
    g_fam      <<<(BB*LL+255)/256, 256, 0, stream>>>(feat, km, ss, sb, wgbuf);
    m_chunksum <<<BB*NG*NC, 256, 0, stream>>>(feat, posph, wgbuf, Vbuf, lval, cmem);
    m_scan     <<<BB*NG*4, 256, 0, stream>>>(cmem);
    m_retrieve <<<BB*NG*NC, 256, 0, stream>>>(feat, posph, wgbuf, Vbuf, lval, cmem,
                                              set_w, pw, lw, total);
    k4_out     <<<BB*LL/8, 256, 0, stream>>>(x, total, ln_g, ln_b, oW, ob, out);
}

// Round 3
// 225.451 us; speedup vs baseline: 1.8464x; 1.3281x over previous
//
#include <hip/hip_runtime.h>
#include <math.h>

// ---------------- problem constants ----------------
#define DD   256
#define NSB  4
#define PPB  4
#define POSB 16
#define LL   2048
#define BB   2
#define NC   8          // time chunks
#define CHK  256        // LL/NC
#define NG   13         // additive groups per batch (cross, 4 banks, 4x pos, 4x ltm), 4 slots each
#define FS   128        // feature row stride (floats)
#define PI_F 3.14159265358979323846f

// feature row offsets (floats)
#define JK_OFF   0
#define JQ_OFF   8
#define KP_OFF   16
#define QP_OFF   48
#define LKP_OFF  80
#define GATE_OFF 112

// workspace layout (float offsets)
#define FEAT_O  0L
#define V_O     524288L                  // BB*LL*FS
#define LV_O    1572864L                 // V_O + BB*LL*DD
#define PPH_O   2621440L                 // LV_O + BB*LL*DD
#define TOT_O   2686976L                 // PPH_O + LL*32
#define CMEM_O  3735552L                 // TOT_O + BB*LL*DD
#define KM_O    CMEM_O                   // km aliases cmem (km dead before m_chunksum runs)
#define WGB_O   4161536L                 // CMEM_O + BB*NG*NC*4*2*DD
#define XH_O    4169728L                 // WGB_O + BB*LL*2 ; ushort region BB*LL*DD (=524288 floats)
#define XL_O    4694016L
#define WTH_O   5218304L                 // 1536*256 ushort = 196608 floats
#define WTL_O   5414912L
#define WS_FLOATS 5611520L               // ~22.4 MB

typedef __attribute__((ext_vector_type(8))) short bf16x8;
typedef __attribute__((ext_vector_type(4))) float f32x4;

__device__ __forceinline__ float sigm(float v){ return 1.0f/(1.0f+expf(-v)); }
__device__ __forceinline__ float gelu_exact(float v){ return 0.5f*v*(1.0f+erff(v*0.70710678118654752f)); }
__device__ __forceinline__ unsigned short f2bf(float f){
    unsigned u = __float_as_uint(f);
    unsigned r = u + 0x7fffu + ((u>>16)&1u);
    return (unsigned short)(r>>16);
}
__device__ __forceinline__ float bf2f(unsigned short h){ return __uint_as_float(((unsigned)h)<<16); }

// ---------------- K0: positional phasor table ----------------
__global__ __launch_bounds__(256) void k0_posph(const float* __restrict__ pf, float* __restrict__ posph){
    int t = blockIdx.x*256 + threadIdx.x;
    if (t >= LL) return;
    #pragma unroll
    for (int j=0;j<POSB;++j){
        float ang = (((float)t * pf[j]) * 2.0f) * PI_F;
        float s,c; sincosf(ang,&s,&c);
        posph[t*32+2*j]   = c;
        posph[t*32+2*j+1] = s;
    }
}

// ---------------- P0: split x into bf16 hi/lo ----------------
__global__ __launch_bounds__(256) void prep_x(const float* __restrict__ x,
                                              unsigned short* __restrict__ xh,
                                              unsigned short* __restrict__ xl){
    long idx = (long)blockIdx.x*256 + threadIdx.x;   // grid exactly BB*LL*DD/256
    float f = x[idx];
    unsigned short h = f2bf(f);
    xh[idx] = h;
    xl[idx] = f2bf(f - bf2f(h));
}

// ---------------- P1: pack + transpose first-layer weights into bf16 hi/lo ----------------
// packed col map: [0,256)=kW1 [256,512)=qW1 [512,768)=lW1 [768,1024)=vW [1024,1280)=lvW
// [1280,1408)=gW1 ; [1408,1536)=zero pad.  Layout: wt[col][K=256]
__global__ __launch_bounds__(256) void prep_w(
    const float* __restrict__ kW1, const float* __restrict__ qW1, const float* __restrict__ lW1,
    const float* __restrict__ vW,  const float* __restrict__ lvW, const float* __restrict__ gW1,
    unsigned short* __restrict__ wth, unsigned short* __restrict__ wtl)
{
    int cg = blockIdx.x;      // global col 0..1535
    int fi = threadIdx.x;
    float w = 0.f;
    if (cg < 1408){
        int m = cg >> 8;                      // 5 for [1280,1536)
        if (m < 5){
            const float* W = (m==0)?kW1:((m==1)?qW1:((m==2)?lW1:((m==3)?vW:lvW)));
            w = W[fi*DD + (cg & 255)];
        } else {
            w = gW1[fi*128 + (cg - 1280)];
        }
    }
    unsigned short h = f2bf(w);
    wth[(long)cg*DD + fi] = h;
    wtl[(long)cg*DD + fi] = f2bf(w - bf2f(h));
}

// ---------------- MLP fused: MFMA GEMM (bf16x2) + nonlinear epilogue ----------------
// grid = 6*128 blocks: mat = blk>>7 (0=k,1=q,2=l,3=v,4=lv,5=gate), bm = blk&127 (32-row tile)
__global__ __launch_bounds__(256) void mlp_fused(
    const unsigned short* __restrict__ xh, const unsigned short* __restrict__ xl,
    const unsigned short* __restrict__ wth, const unsigned short* __restrict__ wtl,
    const float* __restrict__ kb1, const float* __restrict__ kW2, const float* __restrict__ kb2,
    const float* __restrict__ qb1, const float* __restrict__ qW2, const float* __restrict__ qb2,
    const float* __restrict__ lb1, const float* __restrict__ lW2, const float* __restrict__ lb2,
    const float* __restrict__ vb,  const float* __restrict__ lvb,
    const float* __restrict__ gb1, const float* __restrict__ gW2, const float* __restrict__ gb2,
    float* __restrict__ feat, float* __restrict__ Vbuf, float* __restrict__ lvalbuf)
{
    __shared__ float smem[32*257 + 32*16];   // hl[32][257] + ang[32][16]; gate reuses region
    int tid = threadIdx.x, lane = tid & 63, wv = tid >> 6;
    int mat = blockIdx.x >> 7, bm = blockIdx.x & 127;
    int rowg0 = bm*32;
    int colbase = mat*256;                    // mat==5 -> 1280 (gW1)
    int ar = lane & 15, kk = (lane>>4)*8;

    f32x4 acc[2][4];
    #pragma unroll
    for (int i=0;i<2;++i)
        #pragma unroll
        for (int j=0;j<4;++j) acc[i][j] = (f32x4){0.f,0.f,0.f,0.f};

    for (int ksb=0; ksb<8; ++ksb){
        int k = ksb*32 + kk;
        bf16x8 ah[2], al[2], bh[4], bl[4];
        #pragma unroll
        for (int i=0;i<2;++i){
            long off = (long)(rowg0 + i*16 + ar)*DD + k;
            ah[i] = *reinterpret_cast<const bf16x8*>(xh + off);
            al[i] = *reinterpret_cast<const bf16x8*>(xl + off);
        }
        #pragma unroll
        for (int j=0;j<4;++j){
            long off = (long)(colbase + wv*64 + j*16 + ar)*DD + k;   // padded cols -> safe
            bh[j] = *reinterpret_cast<const bf16x8*>(wth + off);
            bl[j] = *reinterpret_cast<const bf16x8*>(wtl + off);
        }
        #pragma unroll
        for (int i=0;i<2;++i)
            #pragma unroll
            for (int j=0;j<4;++j){
                acc[i][j] = __builtin_amdgcn_mfma_f32_16x16x32_bf16(ah[i], bh[j], acc[i][j], 0,0,0);
                acc[i][j] = __builtin_amdgcn_mfma_f32_16x16x32_bf16(ah[i], bl[j], acc[i][j], 0,0,0);
                acc[i][j] = __builtin_amdgcn_mfma_f32_16x16x32_bf16(al[i], bh[j], acc[i][j], 0,0,0);
            }
    }

    // C-layout per m89: reg r of tile(i,j): row = i*16 + (lane>>4)*4 + r, col = wv*64 + j*16 + (lane&15)
    int rl0 = (lane>>4)*4;

    if (mat < 3){
        // ---- k/q/l MLP epilogue: bias+gelu -> LDS, W2 (256->16), tanh, phasors ----
        float (*hl)[257] = (float(*)[257])smem;
        float (*ang)[16] = (float(*)[16])(smem + 32*257);
        const float* b1 = (mat==0)?kb1:((mat==1)?qb1:lb1);
        #pragma unroll
        for (int i=0;i<2;++i)
            #pragma unroll
            for (int j=0;j<4;++j){
                int c = wv*64 + j*16 + ar;
                #pragma unroll
                for (int r=0;r<4;++r)
                    hl[i*16 + rl0 + r][c] = gelu_exact(acc[i][j][r] + b1[c]);
            }
        __syncthreads();
        const float* W2 = (mat==0)?kW2:((mat==1)?qW2:lW2);
        const float* b2 = (mat==0)?kb2:((mat==1)?qb2:lb2);
        int off = (mat==0)?KP_OFF:((mat==1)?QP_OFF:LKP_OFF);
        #pragma unroll
        for (int u=0;u<2;++u){
            int idx = tid + u*256;
            int tok = idx>>4, o = idx&15;
            float s = b2[o];
            #pragma unroll 4
            for (int hh=0;hh<DD;++hh) s += hl[tok][hh]*W2[hh*16+o];
            float a = tanhf(s)*PI_F;
            ang[tok][o] = a;
            float sn,cs; sincosf(a,&sn,&cs);
            long rowg = rowg0 + tok;
            feat[rowg*FS + off + 2*o]   = cs;
            feat[rowg*FS + off + 2*o+1] = sn;
        }
        __syncthreads();
        if (mat<2 && tid<128){
            int tok = tid>>2, p = tid&3;
            float a = ang[tok][p]+ang[tok][4+p]+ang[tok][8+p]+ang[tok][12+p];
            float sn,cs; sincosf(a,&sn,&cs);
            int joff = (mat==0)?JK_OFF:JQ_OFF;
            long rowg = rowg0 + tok;
            feat[rowg*FS + joff + 2*p]   = cs;
            feat[rowg*FS + joff + 2*p+1] = sn;
        }
    } else if (mat < 5){
        // ---- V / ltm_val: bias + direct store ----
        const float* bv = (mat==3)? vb : lvb;
        float* dst = (mat==3)? Vbuf : lvalbuf;
        #pragma unroll
        for (int i=0;i<2;++i)
            #pragma unroll
            for (int j=0;j<4;++j){
                int c = wv*64 + j*16 + ar;
                #pragma unroll
                for (int r=0;r<4;++r)
                    dst[(long)(rowg0 + i*16 + rl0 + r)*DD + c] = acc[i][j][r] + bv[c];
            }
    } else {
        // ---- gate: bias+gelu (128 cols) -> dot-128 -> sigmoid ----
        float (*hg)[132] = (float(*)[132])smem;
        float (*part)[8] = (float(*)[8])(smem + 32*132);
        if (wv < 2){
            #pragma unroll
            for (int i=0;i<2;++i)
                #pragma unroll
                for (int j=0;j<4;++j){
                    int c = wv*64 + j*16 + ar;     // 0..127
                    #pragma unroll
                    for (int r=0;r<4;++r)
                        hg[i*16 + rl0 + r][c] = gelu_exact(acc[i][j][r] + gb1[c]);
                }
        }
        __syncthreads();
        {
            int tok = tid>>3, jj = tid&7;
            float s = 0.f;
            #pragma unroll
            for (int c=0;c<16;++c) s += hg[tok][jj*16+c]*gW2[jj*16+c];
            part[tok][jj] = s;
        }
        __syncthreads();
        if (tid < 32){
            float s = gb2[0];
            #pragma unroll
            for (int j=0;j<8;++j) s += part[tid][j];
            feat[(long)(rowg0+tid)*FS + GATE_OFF] = sigm(s);
        }
    }
}

// ---------------- G-A: parallel exclusive prefix of 40 key channels ----------------
__global__ __launch_bounds__(256) void g_prefix(const float* __restrict__ feat, float* __restrict__ km){
    int b = blockIdx.x / 40, ch = blockIdx.x % 40;
    int off = (ch<8) ? (JK_OFF+ch) : (LKP_OFF + (ch-8));
    int tid = threadIdx.x;
    long rb = (long)b*LL*FS;
    float v[8]; float s = 0.f;
    #pragma unroll
    for (int u=0;u<8;++u){
        v[u] = feat[rb + (long)(tid*8+u)*FS + off];
        s += v[u];
    }
    int lane = tid & 63, w = tid >> 6;
    float xsc = s;
    #pragma unroll
    for (int o=1;o<64;o<<=1){ float y = __shfl_up(xsc,o); if (lane>=o) xsc += y; }
    __shared__ float wsum[4];
    if (lane==63) wsum[w] = xsc;
    __syncthreads();
    float woff = 0.f;
    for (int i=0;i<w;++i) woff += wsum[i];
    float run = (xsc - s) + woff;
    #pragma unroll
    for (int u=0;u<8;++u){
        km[((long)b*LL + tid*8+u)*40 + ch] = run;
        run += v[u];
    }
}

// ---------------- G-B: per-token familiarity + write gates ----------------
__global__ __launch_bounds__(256) void g_fam(
    const float* __restrict__ feat, const float* __restrict__ km,
    const float* __restrict__ ss_p, const float* __restrict__ sb_p,
    float* __restrict__ wgbuf)
{
    int t = blockIdx.x*256 + threadIdx.x;
    if (t >= BB*LL) return;
    int tc = t % LL;
    float ss = ss_p[0], sb = sb_p[0];
    long frow = (long)t*FS;
    const float* kmrow = km + (long)t*40;
    float pcb = fmaxf((float)tc, 1.0f);

    float sr=0.f, si=0.f;
    #pragma unroll
    for (int p=0;p<4;++p){
        float kr = feat[frow+JK_OFF+2*p], ki = feat[frow+JK_OFF+2*p+1];
        float kmr = kmrow[2*p], kmi = kmrow[2*p+1];
        sr += kmr*kr + kmi*ki;
        si += kmi*kr - kmr*ki;
    }
    float res = sqrtf(sr*sr+si*si);
    float fam = fminf(fmaxf(res/(pcb*2.0f),0.f),1.f);
    wgbuf[(long)t*2] = sigm(ss*(0.5f-fam)+sb);

    sr=0.f; si=0.f;
    #pragma unroll
    for (int p=0;p<16;++p){
        float kr = feat[frow+LKP_OFF+2*p], ki = feat[frow+LKP_OFF+2*p+1];
        float kmr = kmrow[8+2*p], kmi = kmrow[8+2*p+1];
        sr += kmr*kr + kmi*ki;
        si += kmi*kr - kmr*ki;
    }
    float res2 = sqrtf(sr*sr+si*si);
    float fam2 = fminf(fmaxf(res2/(pcb*4.0f),0.f),1.f);
    wgbuf[(long)t*2+1] = sigm(ss*(0.5f-fam2)+sb);
}

// ---------------- M-A: per-chunk memory sums ----------------
__global__ __launch_bounds__(256) void m_chunksum(
    const float* __restrict__ feat, const float* __restrict__ posph,
    const float* __restrict__ wgbuf, const float* __restrict__ Vbuf,
    const float* __restrict__ lvalbuf, float* __restrict__ cmem)
{
    int blk = blockIdx.x;
    int b = blk/(NG*NC); int r = blk%(NG*NC); int g = r/NC, c = r%NC;
    int d = threadIdx.x;
    __shared__ float kl[CHK][8];
    __shared__ float gl[CHK];
    long frow = ((long)b*LL + c*CHK)*FS;
    for (int idx=threadIdx.x; idx<CHK*8; idx+=256){
        int t = idx>>3, j = idx&7;
        float v;
        if (g==0)       v = feat[frow + (long)t*FS + JK_OFF + j];
        else if (g<5)   v = feat[frow + (long)t*FS + KP_OFF + (g-1)*8 + j];
        else if (g<9)   v = posph[(long)(c*CHK+t)*32 + (g-5)*8 + j];
        else            v = feat[frow + (long)t*FS + LKP_OFF + (g-9)*8 + j];
        kl[t][j] = v;
    }
    for (int t=threadIdx.x; t<CHK; t+=256){
        float gf;
        if (g<5)      gf = wgbuf[((long)b*LL + c*CHK + t)*2];
        else if (g<9) gf = 1.0f;
        else          gf = wgbuf[((long)b*LL + c*CHK + t)*2 + 1];
        gl[t] = gf;
    }
    __syncthreads();
    const float* vsrc = (g>=9)? lvalbuf : Vbuf;
    long vrow = ((long)b*LL + c*CHK)*DD + d;
    float m0r=0,m0i=0,m1r=0,m1i=0,m2r=0,m2i=0,m3r=0,m3i=0;
    for (int t=0;t<CHK;++t){
        float v = vsrc[vrow + (long)t*DD] * gl[t];
        m0r += kl[t][0]*v; m0i += kl[t][1]*v;
        m1r += kl[t][2]*v; m1i += kl[t][3]*v;
        m2r += kl[t][4]*v; m2i += kl[t][5]*v;
        m3r += kl[t][6]*v; m3i += kl[t][7]*v;
    }
    long ob = (long)blk*8*DD + d;
    cmem[ob+0*DD]=m0r; cmem[ob+1*DD]=m0i;
    cmem[ob+2*DD]=m1r; cmem[ob+3*DD]=m1i;
    cmem[ob+4*DD]=m2r; cmem[ob+5*DD]=m2i;
    cmem[ob+6*DD]=m3r; cmem[ob+7*DD]=m3i;
}

// ---------------- M-B: exclusive scan over chunks (in place) ----------------
__global__ __launch_bounds__(256) void m_scan(float* __restrict__ cmem){
    int line = blockIdx.x;
    int lb = line>>2, slot = line&3, d = threadIdx.x;
    float rr=0.f, ri=0.f;
    for (int c=0;c<NC;++c){
        long a = (((long)(lb*NC + c)*4 + slot)*2)*DD + d;
        float tr = cmem[a], ti = cmem[a+DD];
        cmem[a] = rr; cmem[a+DD] = ri;
        rr += tr; ri += ti;
    }
}

// ---------------- M-C: per-chunk scan + retrieval (atomicAdd into total) ----------------
__global__ __launch_bounds__(256) void m_retrieve(
    const float* __restrict__ feat, const float* __restrict__ posph,
    const float* __restrict__ wgbuf, const float* __restrict__ Vbuf,
    const float* __restrict__ lvalbuf, const float* __restrict__ cmem,
    const float* __restrict__ set_w, const float* __restrict__ pos_w,
    const float* __restrict__ ltm_w, float* __restrict__ total)
{
    int blk = blockIdx.x;
    int b = blk/(NG*NC); int r = blk%(NG*NC); int g = r/NC, c = r%NC;
    int d = threadIdx.x;
    __shared__ float kl[CHK][8];
    __shared__ float ql[CHK][8];
    __shared__ float gl[CHK];
    __shared__ float sl[CHK];
    long frow = ((long)b*LL + c*CHK)*FS;
    for (int idx=threadIdx.x; idx<CHK*8; idx+=256){
        int t = idx>>3, j = idx&7;
        float kv, qv;
        if (g==0){
            kv = feat[frow + (long)t*FS + JK_OFF + j];
            qv = feat[frow + (long)t*FS + JQ_OFF + j];
        } else if (g<5){
            kv = feat[frow + (long)t*FS + KP_OFF + (g-1)*8 + j];
            qv = feat[frow + (long)t*FS + QP_OFF + (g-1)*8 + j];
        } else if (g<9){
            kv = qv = posph[(long)(c*CHK+t)*32 + (g-5)*8 + j];
        } else {
            kv = qv = feat[frow + (long)t*FS + LKP_OFF + (g-9)*8 + j];
        }
        kl[t][j] = kv; ql[t][j] = qv;
    }
    for (int t=threadIdx.x; t<CHK; t+=256){
        int tc = c*CHK + t;
        float gate = feat[frow + (long)t*FS + GATE_OFF];
        float gf, sc;
        if (g<5){
            gf = wgbuf[((long)b*LL+tc)*2];
            if (g==0) sc = gate*0.2f;
            else {
                float w0=expf(set_w[0]),w1=expf(set_w[1]),w2=expf(set_w[2]),w3=expf(set_w[3]);
                float den = w0+w1+w2+w3;
                float wsv = (g==1)?w0:((g==2)?w1:((g==3)?w2:w3));
                sc = gate*0.2f*wsv/den;
            }
        } else if (g<9){
            gf = 1.0f;
            sc = (1.0f-gate)*sigm(pos_w[0]);
        } else {
            gf = wgbuf[((long)b*LL+tc)*2+1];
            sc = sigm(ltm_w[0]) * rsqrtf((float)(tc+1)*16.0f);
        }
        gl[t]=gf; sl[t]=sc;
    }
    __syncthreads();
    const float* vsrc = (g>=9)? lvalbuf : Vbuf;
    long vrow = ((long)b*LL + c*CHK)*DD + d;
    long cb = (long)blk*8*DD + d;
    float m0r=cmem[cb+0*DD], m0i=cmem[cb+1*DD];
    float m1r=cmem[cb+2*DD], m1i=cmem[cb+3*DD];
    float m2r=cmem[cb+4*DD], m2i=cmem[cb+5*DD];
    float m3r=cmem[cb+6*DD], m3i=cmem[cb+7*DD];
    float* tp = total + ((long)b*LL + c*CHK)*DD + d;
    for (int t=0;t<CHK;++t){
        float v = vsrc[vrow + (long)t*DD] * gl[t];
        m0r += kl[t][0]*v; m0i += kl[t][1]*v;
        m1r += kl[t][2]*v; m1i += kl[t][3]*v;
        m2r += kl[t][4]*v; m2i += kl[t][5]*v;
        m3r += kl[t][6]*v; m3i += kl[t][7]*v;
        float rs = m0r*ql[t][0] + m0i*ql[t][1]
                 + m1r*ql[t][2] + m1i*ql[t][3]
                 + m2r*ql[t][4] + m2i*ql[t][5]
                 + m3r*ql[t][6] + m3i*ql[t][7];
        atomicAdd(tp + (long)t*DD, rs*sl[t]);
    }
}

// ---------------- K4: normalize + LN + output projection + residual ----------------
__global__ __launch_bounds__(256) void k4_out(
    const float* __restrict__ x, const float* __restrict__ total,
    const float* __restrict__ ln_g, const float* __restrict__ ln_b,
    const float* __restrict__ oW,  const float* __restrict__ obv,
    float* __restrict__ out)
{
    __shared__ float tn[8][DD];
    int tid = threadIdx.x;
    long base = (long)blockIdx.x*8;
    int wave = tid>>6, lane = tid&63;
    for (int wtok=0; wtok<2; ++wtok){
        int tok = wave*2 + wtok;
        long row = base + tok;
        int tc = (int)(row % LL);
        float inv = rsqrtf((float)(tc+1)*4.0f);
        float4 tv4 = ((const float4*)(total + row*DD))[lane];
        float vals[4] = {tv4.x*inv, tv4.y*inv, tv4.z*inv, tv4.w*inv};
        float s=0.f, s2=0.f;
        #pragma unroll
        for (int k=0;k<4;++k){ s += vals[k]; s2 += vals[k]*vals[k]; }
        for (int o=1;o<64;o<<=1){ s += __shfl_xor(s,o); s2 += __shfl_xor(s2,o); }
        float mu = s/256.f, var = s2/256.f - mu*mu;
        float rstd = rsqrtf(var + 1e-5f);
        float4 w;
        w.x = (vals[0]-mu)*rstd*ln_g[lane*4+0] + ln_b[lane*4+0];
        w.y = (vals[1]-mu)*rstd*ln_g[lane*4+1] + ln_b[lane*4+1];
        w.z = (vals[2]-mu)*rstd*ln_g[lane*4+2] + ln_b[lane*4+2];
        w.w = (vals[3]-mu)*rstd*ln_g[lane*4+3] + ln_b[lane*4+3];
        ((float4*)&tn[tok][0])[lane] = w;
    }
    __syncthreads();
    float acc[8];
    #pragma unroll
    for (int tok=0;tok<8;++tok) acc[tok]=obv[tid];
    #pragma unroll 4
    for (int i=0;i<DD;++i){
        float w = oW[i*DD+tid];
        #pragma unroll
        for (int tok=0;tok<8;++tok) acc[tok] += tn[tok][i]*w;
    }
    for (int tok=0;tok<8;++tok){
        long row = base+tok;
        out[row*DD+tid] = x[row*DD+tid] + acc[tok];
    }
}

// ---------------- launch ----------------
extern "C" void kernel_launch(void* const* d_in, const int* in_sizes, int n_in,
                              void* d_out, int out_size, void* d_ws, size_t ws_size,
                              hipStream_t stream)
{
    const float* x    = (const float*)d_in[0];
    const float* kW1  = (const float*)d_in[1];
    const float* kb1  = (const float*)d_in[2];
    const float* kW2  = (const float*)d_in[3];
    const float* kb2  = (const float*)d_in[4];
    const float* qW1  = (const float*)d_in[5];
    const float* qb1  = (const float*)d_in[6];
    const float* qW2  = (const float*)d_in[7];
    const float* qb2  = (const float*)d_in[8];
    const float* vW   = (const float*)d_in[9];
    const float* vb   = (const float*)d_in[10];
    const float* ln_g = (const float*)d_in[11];
    const float* ln_b = (const float*)d_in[12];
    const float* oW   = (const float*)d_in[13];
    const float* ob   = (const float*)d_in[14];
    const float* set_w= (const float*)d_in[15];
    const float* pf   = (const float*)d_in[16];
    const float* pw   = (const float*)d_in[17];
    const float* gW1  = (const float*)d_in[18];
    const float* gb1  = (const float*)d_in[19];
    const float* gW2  = (const float*)d_in[20];
    const float* gb2  = (const float*)d_in[21];
    const float* lW1  = (const float*)d_in[22];
    const float* lb1  = (const float*)d_in[23];
    const float* lW2  = (const float*)d_in[24];
    const float* lb2  = (const float*)d_in[25];
    const float* lvW  = (const float*)d_in[26];
    const float* lvb  = (const float*)d_in[27];
    const float* ss   = (const float*)d_in[28];
    const float* sb   = (const float*)d_in[29];
    const float* lw   = (const float*)d_in[30];
    float* out = (float*)d_out;

    float* ws    = (float*)d_ws;
    float* feat  = ws + FEAT_O;
    float* Vbuf  = ws + V_O;
    float* lval  = ws + LV_O;
    float* posph = ws + PPH_O;
    float* total = ws + TOT_O;
    float* cmem  = ws + CMEM_O;
    float* km    = ws + KM_O;
    float* wgbuf = ws + WGB_O;
    unsigned short* xh  = (unsigned short*)(ws + XH_O);
    unsigned short* xl  = (unsigned short*)(ws + XL_O);
    unsigned short* wth = (unsigned short*)(ws + WTH_O);
    unsigned short* wtl = (unsigned short*)(ws + WTL_O);

    (void)in_sizes; (void)n_in; (void)out_size; (void)ws_size;

    hipMemsetAsync(total, 0, (size_t)BB*LL*DD*sizeof(float), stream);

    k0_posph <<<LL/256, 256, 0, stream>>>(pf, posph);
    prep_x   <<<BB*LL*DD/256, 256, 0, stream>>>(x, xh, xl);
    prep_w   <<<1536, 256, 0, stream>>>(kW1,qW1,lW1,vW,lvW,gW1, wth, wtl);
    mlp_fused<<<6*128, 256, 0, stream>>>(xh,xl,wth,wtl,
                                         kb1,kW2,kb2, qb1,qW2,qb2, lb1,lW2,lb2,
                                         vb,lvb, gb1,gW2,gb2, feat, Vbuf, lval);
    g_prefix <<<BB*40, 256, 0, stream>>>(feat, km);
    g_fam    <<<(BB*LL+255)/256, 256, 0, stream>>>(feat, km, ss, sb, wgbuf);
    m_chunksum <<<BB*NG*NC, 256, 0, stream>>>(feat, posph, wgbuf, Vbuf, lval, cmem);
    m_scan     <<<BB*NG*4, 256, 0, stream>>>(cmem);
    m_retrieve <<<BB*NG*NC, 256, 0, stream>>>(feat, posph, wgbuf, Vbuf, lval, cmem,
                                              set_w, pw, lw, total);
    k4_out     <<<BB*LL/8, 256, 0, stream>>>(x, total, ln_g, ln_b, oW, ob, out);
}

// Round 4
// 173.361 us; speedup vs baseline: 2.4012x; 1.3005x over previous
//
#include <hip/hip_runtime.h>
#include <math.h>

// ---------------- problem constants ----------------
#define DD   256
#define NSB  4
#define PPB  4
#define POSB 16
#define LL   2048
#define BB   2
#define NC   32         // time chunks
#define CHK  64         // LL/NC
#define NG   13         // groups: 0=cross, 1-4 banks, 5-8 pos, 9-12 ltm (4 complex slots each)
#define FS   128        // feature row stride (floats)
#define PI_F 3.14159265358979323846f

// feature row offsets (floats)
#define JK_OFF   0
#define JQ_OFF   8
#define KP_OFF   16
#define QP_OFF   48
#define LKP_OFF  80
#define GATE_OFF 112

// workspace layout (float offsets)
#define FEAT_O  0L
#define V_O     524288L                  // BB*LL*FS
#define LV_O    1572864L                 // V_O + BB*LL*DD
#define PPH_O   2621440L                 // LV_O + BB*LL*DD
#define TOT_O   2686976L                 // PPH_O + LL*32
#define CMEM_O  3735552L                 // TOT_O + BB*LL*DD ; size BB*NG*NC*8*DD = 1703936
#define WGB_O   5439488L                 // CMEM_O + 1703936
#define WS_FLOATS 5447680L               // WGB_O + BB*LL*2  (~21.8 MB)
// aliases inside the CMEM region (all dead before m_chunksum writes cmem):
#define KM_O    CMEM_O                   // g_prefix output, BB*LL*40 = 163840 floats
#define XH_O    CMEM_O                   // prep buffers, consumed by mlp_fused
#define XL_O    (CMEM_O + 524288L)
#define WTH_O   (CMEM_O + 1048576L)
#define WTL_O   (CMEM_O + 1245184L)      // end 1441792 <= 1703936

typedef __attribute__((ext_vector_type(8))) short bf16x8;
typedef __attribute__((ext_vector_type(4))) float f32x4;

__device__ __forceinline__ float sigm(float v){ return 1.0f/(1.0f+expf(-v)); }
__device__ __forceinline__ float gelu_exact(float v){ return 0.5f*v*(1.0f+erff(v*0.70710678118654752f)); }
__device__ __forceinline__ unsigned short f2bf(float f){
    unsigned u = __float_as_uint(f);
    unsigned r = u + 0x7fffu + ((u>>16)&1u);
    return (unsigned short)(r>>16);
}
__device__ __forceinline__ float bf2f(unsigned short h){ return __uint_as_float(((unsigned)h)<<16); }

// ---------------- K0: positional phasor table ----------------
__global__ __launch_bounds__(256) void k0_posph(const float* __restrict__ pf, float* __restrict__ posph){
    int t = blockIdx.x*256 + threadIdx.x;
    if (t >= LL) return;
    #pragma unroll
    for (int j=0;j<POSB;++j){
        float ang = (((float)t * pf[j]) * 2.0f) * PI_F;
        float s,c; sincosf(ang,&s,&c);
        posph[t*32+2*j]   = c;
        posph[t*32+2*j+1] = s;
    }
}

// ---------------- P0: split x into bf16 hi/lo ----------------
__global__ __launch_bounds__(256) void prep_x(const float* __restrict__ x,
                                              unsigned short* __restrict__ xh,
                                              unsigned short* __restrict__ xl){
    long idx = (long)blockIdx.x*256 + threadIdx.x;
    float f = x[idx];
    unsigned short h = f2bf(f);
    xh[idx] = h;
    xl[idx] = f2bf(f - bf2f(h));
}

// ---------------- P1: pack + transpose first-layer weights into bf16 hi/lo ----------------
__global__ __launch_bounds__(256) void prep_w(
    const float* __restrict__ kW1, const float* __restrict__ qW1, const float* __restrict__ lW1,
    const float* __restrict__ vW,  const float* __restrict__ lvW, const float* __restrict__ gW1,
    unsigned short* __restrict__ wth, unsigned short* __restrict__ wtl)
{
    int cg = blockIdx.x;      // global col 0..1535
    int fi = threadIdx.x;
    float w = 0.f;
    if (cg < 1408){
        int m = cg >> 8;
        if (m < 5){
            const float* W = (m==0)?kW1:((m==1)?qW1:((m==2)?lW1:((m==3)?vW:lvW)));
            w = W[fi*DD + (cg & 255)];
        } else {
            w = gW1[fi*128 + (cg - 1280)];
        }
    }
    unsigned short h = f2bf(w);
    wth[(long)cg*DD + fi] = h;
    wtl[(long)cg*DD + fi] = f2bf(w - bf2f(h));
}

// ---------------- MLP fused: MFMA GEMM (bf16x2) + nonlinear epilogue ----------------
__global__ __launch_bounds__(256) void mlp_fused(
    const unsigned short* __restrict__ xh, const unsigned short* __restrict__ xl,
    const unsigned short* __restrict__ wth, const unsigned short* __restrict__ wtl,
    const float* __restrict__ kb1, const float* __restrict__ kW2, const float* __restrict__ kb2,
    const float* __restrict__ qb1, const float* __restrict__ qW2, const float* __restrict__ qb2,
    const float* __restrict__ lb1, const float* __restrict__ lW2, const float* __restrict__ lb2,
    const float* __restrict__ vb,  const float* __restrict__ lvb,
    const float* __restrict__ gb1, const float* __restrict__ gW2, const float* __restrict__ gb2,
    float* __restrict__ feat, float* __restrict__ Vbuf, float* __restrict__ lvalbuf)
{
    __shared__ float smem[32*257 + 32*16];
    int tid = threadIdx.x, lane = tid & 63, wv = tid >> 6;
    int mat = blockIdx.x >> 7, bm = blockIdx.x & 127;
    int rowg0 = bm*32;
    int colbase = mat*256;
    int ar = lane & 15, kk = (lane>>4)*8;

    f32x4 acc[2][4];
    #pragma unroll
    for (int i=0;i<2;++i)
        #pragma unroll
        for (int j=0;j<4;++j) acc[i][j] = (f32x4){0.f,0.f,0.f,0.f};

    for (int ksb=0; ksb<8; ++ksb){
        int k = ksb*32 + kk;
        bf16x8 ah[2], al[2], bh[4], bl[4];
        #pragma unroll
        for (int i=0;i<2;++i){
            long off = (long)(rowg0 + i*16 + ar)*DD + k;
            ah[i] = *reinterpret_cast<const bf16x8*>(xh + off);
            al[i] = *reinterpret_cast<const bf16x8*>(xl + off);
        }
        #pragma unroll
        for (int j=0;j<4;++j){
            long off = (long)(colbase + wv*64 + j*16 + ar)*DD + k;
            bh[j] = *reinterpret_cast<const bf16x8*>(wth + off);
            bl[j] = *reinterpret_cast<const bf16x8*>(wtl + off);
        }
        #pragma unroll
        for (int i=0;i<2;++i)
            #pragma unroll
            for (int j=0;j<4;++j){
                acc[i][j] = __builtin_amdgcn_mfma_f32_16x16x32_bf16(ah[i], bh[j], acc[i][j], 0,0,0);
                acc[i][j] = __builtin_amdgcn_mfma_f32_16x16x32_bf16(ah[i], bl[j], acc[i][j], 0,0,0);
                acc[i][j] = __builtin_amdgcn_mfma_f32_16x16x32_bf16(al[i], bh[j], acc[i][j], 0,0,0);
            }
    }

    int rl0 = (lane>>4)*4;

    if (mat < 3){
        float (*hl)[257] = (float(*)[257])smem;
        float (*ang)[16] = (float(*)[16])(smem + 32*257);
        const float* b1 = (mat==0)?kb1:((mat==1)?qb1:lb1);
        #pragma unroll
        for (int i=0;i<2;++i)
            #pragma unroll
            for (int j=0;j<4;++j){
                int c = wv*64 + j*16 + ar;
                #pragma unroll
                for (int r=0;r<4;++r)
                    hl[i*16 + rl0 + r][c] = gelu_exact(acc[i][j][r] + b1[c]);
            }
        __syncthreads();
        const float* W2 = (mat==0)?kW2:((mat==1)?qW2:lW2);
        const float* b2 = (mat==0)?kb2:((mat==1)?qb2:lb2);
        int off = (mat==0)?KP_OFF:((mat==1)?QP_OFF:LKP_OFF);
        #pragma unroll
        for (int u=0;u<2;++u){
            int idx = tid + u*256;
            int tok = idx>>4, o = idx&15;
            float s = b2[o];
            #pragma unroll 4
            for (int hh=0;hh<DD;++hh) s += hl[tok][hh]*W2[hh*16+o];
            float a = tanhf(s)*PI_F;
            ang[tok][o] = a;
            float sn,cs; sincosf(a,&sn,&cs);
            long rowg = rowg0 + tok;
            feat[rowg*FS + off + 2*o]   = cs;
            feat[rowg*FS + off + 2*o+1] = sn;
        }
        __syncthreads();
        if (mat<2 && tid<128){
            int tok = tid>>2, p = tid&3;
            float a = ang[tok][p]+ang[tok][4+p]+ang[tok][8+p]+ang[tok][12+p];
            float sn,cs; sincosf(a,&sn,&cs);
            int joff = (mat==0)?JK_OFF:JQ_OFF;
            long rowg = rowg0 + tok;
            feat[rowg*FS + joff + 2*p]   = cs;
            feat[rowg*FS + joff + 2*p+1] = sn;
        }
    } else if (mat < 5){
        const float* bv = (mat==3)? vb : lvb;
        float* dst = (mat==3)? Vbuf : lvalbuf;
        #pragma unroll
        for (int i=0;i<2;++i)
            #pragma unroll
            for (int j=0;j<4;++j){
                int c = wv*64 + j*16 + ar;
                #pragma unroll
                for (int r=0;r<4;++r)
                    dst[(long)(rowg0 + i*16 + rl0 + r)*DD + c] = acc[i][j][r] + bv[c];
            }
    } else {
        float (*hg)[132] = (float(*)[132])smem;
        float (*part)[8] = (float(*)[8])(smem + 32*132);
        if (wv < 2){
            #pragma unroll
            for (int i=0;i<2;++i)
                #pragma unroll
                for (int j=0;j<4;++j){
                    int c = wv*64 + j*16 + ar;
                    #pragma unroll
                    for (int r=0;r<4;++r)
                        hg[i*16 + rl0 + r][c] = gelu_exact(acc[i][j][r] + gb1[c]);
                }
        }
        __syncthreads();
        {
            int tok = tid>>3, jj = tid&7;
            float s = 0.f;
            #pragma unroll
            for (int c=0;c<16;++c) s += hg[tok][jj*16+c]*gW2[jj*16+c];
            part[tok][jj] = s;
        }
        __syncthreads();
        if (tid < 32){
            float s = gb2[0];
            #pragma unroll
            for (int j=0;j<8;++j) s += part[tid][j];
            feat[(long)(rowg0+tid)*FS + GATE_OFF] = sigm(s);
        }
    }
}

// ---------------- G-A: parallel exclusive prefix of 40 key channels ----------------
__global__ __launch_bounds__(256) void g_prefix(const float* __restrict__ feat, float* __restrict__ km){
    int b = blockIdx.x / 40, ch = blockIdx.x % 40;
    int off = (ch<8) ? (JK_OFF+ch) : (LKP_OFF + (ch-8));
    int tid = threadIdx.x;
    long rb = (long)b*LL*FS;
    float v[8]; float s = 0.f;
    #pragma unroll
    for (int u=0;u<8;++u){
        v[u] = feat[rb + (long)(tid*8+u)*FS + off];
        s += v[u];
    }
    int lane = tid & 63, w = tid >> 6;
    float xsc = s;
    #pragma unroll
    for (int o=1;o<64;o<<=1){ float y = __shfl_up(xsc,o); if (lane>=o) xsc += y; }
    __shared__ float wsum[4];
    if (lane==63) wsum[w] = xsc;
    __syncthreads();
    float woff = 0.f;
    for (int i=0;i<w;++i) woff += wsum[i];
    float run = (xsc - s) + woff;
    #pragma unroll
    for (int u=0;u<8;++u){
        km[((long)b*LL + tid*8+u)*40 + ch] = run;
        run += v[u];
    }
}

// ---------------- G-B: per-token familiarity + write gates ----------------
__global__ __launch_bounds__(256) void g_fam(
    const float* __restrict__ feat, const float* __restrict__ km,
    const float* __restrict__ ss_p, const float* __restrict__ sb_p,
    float* __restrict__ wgbuf)
{
    int t = blockIdx.x*256 + threadIdx.x;
    if (t >= BB*LL) return;
    int tc = t % LL;
    float ss = ss_p[0], sb = sb_p[0];
    long frow = (long)t*FS;
    const float* kmrow = km + (long)t*40;
    float pcb = fmaxf((float)tc, 1.0f);

    float sr=0.f, si=0.f;
    #pragma unroll
    for (int p=0;p<4;++p){
        float kr = feat[frow+JK_OFF+2*p], ki = feat[frow+JK_OFF+2*p+1];
        float kmr = kmrow[2*p], kmi = kmrow[2*p+1];
        sr += kmr*kr + kmi*ki;
        si += kmi*kr - kmr*ki;
    }
    float res = sqrtf(sr*sr+si*si);
    float fam = fminf(fmaxf(res/(pcb*2.0f),0.f),1.f);
    wgbuf[(long)t*2] = sigm(ss*(0.5f-fam)+sb);

    sr=0.f; si=0.f;
    #pragma unroll
    for (int p=0;p<16;++p){
        float kr = feat[frow+LKP_OFF+2*p], ki = feat[frow+LKP_OFF+2*p+1];
        float kmr = kmrow[8+2*p], kmi = kmrow[8+2*p+1];
        sr += kmr*kr + kmi*ki;
        si += kmi*kr - kmr*ki;
    }
    float res2 = sqrtf(sr*sr+si*si);
    float fam2 = fminf(fmaxf(res2/(pcb*4.0f),0.f),1.f);
    wgbuf[(long)t*2+1] = sigm(ss*(0.5f-fam2)+sb);
}

// ---------------- M-A: per-chunk memory sums (group-parallel) ----------------
__global__ __launch_bounds__(256) void m_chunksum(
    const float* __restrict__ feat, const float* __restrict__ posph,
    const float* __restrict__ wgbuf, const float* __restrict__ Vbuf,
    const float* __restrict__ lvalbuf, float* __restrict__ cmem)
{
    int blk = blockIdx.x;
    int b = blk/(NG*NC); int r = blk%(NG*NC); int g = r/NC, c = r%NC;
    int d = threadIdx.x;
    __shared__ float kl[CHK][8];
    __shared__ float gl[CHK];
    long frow = ((long)b*LL + c*CHK)*FS;
    for (int idx=threadIdx.x; idx<CHK*8; idx+=256){
        int t = idx>>3, j = idx&7;
        float v;
        if (g==0)       v = feat[frow + (long)t*FS + JK_OFF + j];
        else if (g<5)   v = feat[frow + (long)t*FS + KP_OFF + (g-1)*8 + j];
        else if (g<9)   v = posph[(long)(c*CHK+t)*32 + (g-5)*8 + j];
        else            v = feat[frow + (long)t*FS + LKP_OFF + (g-9)*8 + j];
        kl[t][j] = v;
    }
    for (int t=threadIdx.x; t<CHK; t+=256){
        float gf;
        if (g<5)      gf = wgbuf[((long)b*LL + c*CHK + t)*2];
        else if (g<9) gf = 1.0f;
        else          gf = wgbuf[((long)b*LL + c*CHK + t)*2 + 1];
        gl[t] = gf;
    }
    __syncthreads();
    const float* vsrc = (g>=9)? lvalbuf : Vbuf;
    long vrow = ((long)b*LL + c*CHK)*DD + d;
    float m0r=0,m0i=0,m1r=0,m1i=0,m2r=0,m2i=0,m3r=0,m3i=0;
    #pragma unroll 8
    for (int t=0;t<CHK;++t){
        float v = vsrc[vrow + (long)t*DD] * gl[t];
        m0r += kl[t][0]*v; m0i += kl[t][1]*v;
        m1r += kl[t][2]*v; m1i += kl[t][3]*v;
        m2r += kl[t][4]*v; m2i += kl[t][5]*v;
        m3r += kl[t][6]*v; m3i += kl[t][7]*v;
    }
    long ob = (long)blk*8*DD + d;
    cmem[ob+0*DD]=m0r; cmem[ob+1*DD]=m0i;
    cmem[ob+2*DD]=m1r; cmem[ob+3*DD]=m1i;
    cmem[ob+4*DD]=m2r; cmem[ob+5*DD]=m2i;
    cmem[ob+6*DD]=m3r; cmem[ob+7*DD]=m3i;
}

// ---------------- M-B: exclusive scan over chunks (in place) ----------------
__global__ __launch_bounds__(256) void m_scan(float* __restrict__ cmem){
    int line = blockIdx.x;            // (b*NG+g)*4 + slot
    int lb = line>>2, slot = line&3, d = threadIdx.x;
    float rr=0.f, ri=0.f;
    for (int c=0;c<NC;++c){
        long a = (((long)(lb*NC + c)*4 + slot)*2)*DD + d;
        float tr = cmem[a], ti = cmem[a+DD];
        cmem[a] = rr; cmem[a+DD] = ri;
        rr += tr; ri += ti;
    }
}

// ---------------- M-C: family-fused per-chunk scan + retrieval ----------------
// grid = BB*3*NC; fam 0 = cross+banks (Vbuf), 1 = pos (Vbuf), 2 = ltm (lval)
__global__ __launch_bounds__(256) void m_retrieve_fam(
    const float* __restrict__ feat, const float* __restrict__ posph,
    const float* __restrict__ wgbuf, const float* __restrict__ Vbuf,
    const float* __restrict__ lvalbuf, const float* __restrict__ cmem,
    const float* __restrict__ set_w, const float* __restrict__ pos_w,
    const float* __restrict__ ltm_w, float* __restrict__ total)
{
    int blk = blockIdx.x;
    int b = blk/(3*NC); int r = blk%(3*NC); int fam = r/NC, c = r%NC;
    int d = threadIdx.x;
    __shared__ float s_k0[CHK][16];   // fam0: jk(0..7) + jq(8..15)
    __shared__ float s_kb[CHK][32];   // fam0: bank k; fam1: posph; fam2: lkp
    __shared__ float s_qb[CHK][32];   // fam0 only: bank q
    __shared__ float s_sc[CHK][2];    // per-t gate/scale values
    long frow = ((long)b*LL + c*CHK)*FS;

    for (int idx=threadIdx.x; idx<CHK*32; idx+=256){
        int t = idx>>5, j = idx&31;
        if (fam==0){
            s_kb[t][j] = feat[frow + (long)t*FS + KP_OFF + j];
            s_qb[t][j] = feat[frow + (long)t*FS + QP_OFF + j];
        } else if (fam==1){
            s_kb[t][j] = posph[(long)(c*CHK+t)*32 + j];
        } else {
            s_kb[t][j] = feat[frow + (long)t*FS + LKP_OFF + j];
        }
    }
    if (fam==0){
        for (int idx=threadIdx.x; idx<CHK*16; idx+=256){
            int t = idx>>4, j = idx&15;
            s_k0[t][j] = feat[frow + (long)t*FS + JK_OFF + j];  // JK then JQ contiguous
        }
    }
    for (int t=threadIdx.x; t<CHK; t+=256){
        int tc = c*CHK + t;
        float gate = feat[frow + (long)t*FS + GATE_OFF];
        if (fam==0){
            s_sc[t][0] = wgbuf[((long)b*LL+tc)*2];      // write gate
            s_sc[t][1] = gate*0.2f;                     // output scale
        } else if (fam==1){
            s_sc[t][0] = (1.0f-gate)*sigm(pos_w[0]);
            s_sc[t][1] = 0.f;
        } else {
            s_sc[t][0] = wgbuf[((long)b*LL+tc)*2+1];
            s_sc[t][1] = sigm(ltm_w[0]) * rsqrtf((float)(tc+1)*16.0f);
        }
    }
    __syncthreads();

    long vrow = ((long)b*LL + c*CHK)*DD + d;
    float* tp = total + ((long)b*LL + c*CHK)*DD + d;

    if (fam == 0){
        float w0=expf(set_w[0]),w1=expf(set_w[1]),w2=expf(set_w[2]),w3=expf(set_w[3]);
        float den = w0+w1+w2+w3;
        float wn[4] = {w0/den, w1/den, w2/den, w3/den};
        float cr[4], ci[4], br[4][4], bi[4][4];
        #pragma unroll
        for (int s=0;s<4;++s){
            long cb0 = (((long)(b*NG+0)*NC + c)*8 + 2*s)*DD + d;
            cr[s] = cmem[cb0]; ci[s] = cmem[cb0+DD];
        }
        #pragma unroll
        for (int g=0;g<4;++g)
            #pragma unroll
            for (int s=0;s<4;++s){
                long cb = (((long)(b*NG+1+g)*NC + c)*8 + 2*s)*DD + d;
                br[g][s] = cmem[cb]; bi[g][s] = cmem[cb+DD];
            }
        #pragma unroll 4
        for (int t=0;t<CHK;++t){
            float v = Vbuf[vrow + (long)t*DD];
            float vg = v * s_sc[t][0];
            float rsc = 0.f, rb0=0.f, rb1=0.f, rb2=0.f, rb3=0.f;
            #pragma unroll
            for (int s=0;s<4;++s){
                cr[s] += s_k0[t][2*s]*vg; ci[s] += s_k0[t][2*s+1]*vg;
                rsc += cr[s]*s_k0[t][8+2*s] + ci[s]*s_k0[t][8+2*s+1];
            }
            #pragma unroll
            for (int s=0;s<4;++s){
                br[0][s] += s_kb[t][2*s]*vg;    bi[0][s] += s_kb[t][2*s+1]*vg;
                rb0 += br[0][s]*s_qb[t][2*s] + bi[0][s]*s_qb[t][2*s+1];
                br[1][s] += s_kb[t][8+2*s]*vg;  bi[1][s] += s_kb[t][8+2*s+1]*vg;
                rb1 += br[1][s]*s_qb[t][8+2*s] + bi[1][s]*s_qb[t][8+2*s+1];
                br[2][s] += s_kb[t][16+2*s]*vg; bi[2][s] += s_kb[t][16+2*s+1]*vg;
                rb2 += br[2][s]*s_qb[t][16+2*s] + bi[2][s]*s_qb[t][16+2*s+1];
                br[3][s] += s_kb[t][24+2*s]*vg; bi[3][s] += s_kb[t][24+2*s+1]*vg;
                rb3 += br[3][s]*s_qb[t][24+2*s] + bi[3][s]*s_qb[t][24+2*s+1];
            }
            float rs = s_sc[t][1]*(rsc + rb0*wn[0] + rb1*wn[1] + rb2*wn[2] + rb3*wn[3]);
            atomicAdd(tp + (long)t*DD, rs);
        }
    } else {
        const float* vsrc = (fam==2)? lvalbuf : Vbuf;
        int g0 = (fam==1)? 5 : 9;
        float mr[16], mi[16];
        #pragma unroll
        for (int g=0;g<4;++g)
            #pragma unroll
            for (int s=0;s<4;++s){
                long cb = (((long)(b*NG+g0+g)*NC + c)*8 + 2*s)*DD + d;
                mr[g*4+s] = cmem[cb]; mi[g*4+s] = cmem[cb+DD];
            }
        #pragma unroll 4
        for (int t=0;t<CHK;++t){
            float v = vsrc[vrow + (long)t*DD];
            float vg = (fam==2)? v*s_sc[t][0] : v;
            float rs = 0.f;
            #pragma unroll
            for (int j=0;j<16;++j){
                mr[j] += s_kb[t][2*j]*vg; mi[j] += s_kb[t][2*j+1]*vg;
                rs += mr[j]*s_kb[t][2*j] + mi[j]*s_kb[t][2*j+1];
            }
            float sc = (fam==2)? s_sc[t][1] : s_sc[t][0];
            atomicAdd(tp + (long)t*DD, rs*sc);
        }
    }
}

// ---------------- K4: normalize + LN + output projection + residual ----------------
__global__ __launch_bounds__(256) void k4_out(
    const float* __restrict__ x, const float* __restrict__ total,
    const float* __restrict__ ln_g, const float* __restrict__ ln_b,
    const float* __restrict__ oW,  const float* __restrict__ obv,
    float* __restrict__ out)
{
    __shared__ float tn[8][DD];
    int tid = threadIdx.x;
    long base = (long)blockIdx.x*8;
    int wave = tid>>6, lane = tid&63;
    for (int wtok=0; wtok<2; ++wtok){
        int tok = wave*2 + wtok;
        long row = base + tok;
        int tc = (int)(row % LL);
        float inv = rsqrtf((float)(tc+1)*4.0f);
        float4 tv4 = ((const float4*)(total + row*DD))[lane];
        float vals[4] = {tv4.x*inv, tv4.y*inv, tv4.z*inv, tv4.w*inv};
        float s=0.f, s2=0.f;
        #pragma unroll
        for (int k=0;k<4;++k){ s += vals[k]; s2 += vals[k]*vals[k]; }
        for (int o=1;o<64;o<<=1){ s += __shfl_xor(s,o); s2 += __shfl_xor(s2,o); }
        float mu = s/256.f, var = s2/256.f - mu*mu;
        float rstd = rsqrtf(var + 1e-5f);
        float4 w;
        w.x = (vals[0]-mu)*rstd*ln_g[lane*4+0] + ln_b[lane*4+0];
        w.y = (vals[1]-mu)*rstd*ln_g[lane*4+1] + ln_b[lane*4+1];
        w.z = (vals[2]-mu)*rstd*ln_g[lane*4+2] + ln_b[lane*4+2];
        w.w = (vals[3]-mu)*rstd*ln_g[lane*4+3] + ln_b[lane*4+3];
        ((float4*)&tn[tok][0])[lane] = w;
    }
    __syncthreads();
    float acc[8];
    #pragma unroll
    for (int tok=0;tok<8;++tok) acc[tok]=obv[tid];
    #pragma unroll 4
    for (int i=0;i<DD;++i){
        float w = oW[i*DD+tid];
        #pragma unroll
        for (int tok=0;tok<8;++tok) acc[tok] += tn[tok][i]*w;
    }
    for (int tok=0;tok<8;++tok){
        long row = base+tok;
        out[row*DD+tid] = x[row*DD+tid] + acc[tok];
    }
}

// ---------------- launch ----------------
extern "C" void kernel_launch(void* const* d_in, const int* in_sizes, int n_in,
                              void* d_out, int out_size, void* d_ws, size_t ws_size,
                              hipStream_t stream)
{
    const float* x    = (const float*)d_in[0];
    const float* kW1  = (const float*)d_in[1];
    const float* kb1  = (const float*)d_in[2];
    const float* kW2  = (const float*)d_in[3];
    const float* kb2  = (const float*)d_in[4];
    const float* qW1  = (const float*)d_in[5];
    const float* qb1  = (const float*)d_in[6];
    const float* qW2  = (const float*)d_in[7];
    const float* qb2  = (const float*)d_in[8];
    const float* vW   = (const float*)d_in[9];
    const float* vb   = (const float*)d_in[10];
    const float* ln_g = (const float*)d_in[11];
    const float* ln_b = (const float*)d_in[12];
    const float* oW   = (const float*)d_in[13];
    const float* ob   = (const float*)d_in[14];
    const float* set_w= (const float*)d_in[15];
    const float* pf   = (const float*)d_in[16];
    const float* pw   = (const float*)d_in[17];
    const float* gW1  = (const float*)d_in[18];
    const float* gb1  = (const float*)d_in[19];
    const float* gW2  = (const float*)d_in[20];
    const float* gb2  = (const float*)d_in[21];
    const float* lW1  = (const float*)d_in[22];
    const float* lb1  = (const float*)d_in[23];
    const float* lW2  = (const float*)d_in[24];
    const float* lb2  = (const float*)d_in[25];
    const float* lvW  = (const float*)d_in[26];
    const float* lvb  = (const float*)d_in[27];
    const float* ss   = (const float*)d_in[28];
    const float* sb   = (const float*)d_in[29];
    const float* lw   = (const float*)d_in[30];
    float* out = (float*)d_out;

    float* ws    = (float*)d_ws;
    float* feat  = ws + FEAT_O;
    float* Vbuf  = ws + V_O;
    float* lval  = ws + LV_O;
    float* posph = ws + PPH_O;
    float* total = ws + TOT_O;
    float* cmem  = ws + CMEM_O;
    float* km    = ws + KM_O;
    float* wgbuf = ws + WGB_O;
    unsigned short* xh  = (unsigned short*)(ws + XH_O);
    unsigned short* xl  = (unsigned short*)(ws + XL_O);
    unsigned short* wth = (unsigned short*)(ws + WTH_O);
    unsigned short* wtl = (unsigned short*)(ws + WTL_O);

    (void)in_sizes; (void)n_in; (void)out_size; (void)ws_size;

    hipMemsetAsync(total, 0, (size_t)BB*LL*DD*sizeof(float), stream);

    k0_posph <<<LL/256, 256, 0, stream>>>(pf, posph);
    prep_x   <<<BB*LL*DD/256, 256, 0, stream>>>(x, xh, xl);
    prep_w   <<<1536, 256, 0, stream>>>(kW1,qW1,lW1,vW,lvW,gW1, wth, wtl);
    mlp_fused<<<6*128, 256, 0, stream>>>(xh,xl,wth,wtl,
                                         kb1,kW2,kb2, qb1,qW2,qb2, lb1,lW2,lb2,
                                         vb,lvb, gb1,gW2,gb2, feat, Vbuf, lval);
    g_prefix <<<BB*40, 256, 0, stream>>>(feat, km);
    g_fam    <<<(BB*LL+255)/256, 256, 0, stream>>>(feat, km, ss, sb, wgbuf);
    m_chunksum <<<BB*NG*NC, 256, 0, stream>>>(feat, posph, wgbuf, Vbuf, lval, cmem);
    m_scan     <<<BB*NG*4, 256, 0, stream>>>(cmem);
    m_retrieve_fam <<<BB*3*NC, 256, 0, stream>>>(feat, posph, wgbuf, Vbuf, lval, cmem,
                                                 set_w, pw, lw, total);
    k4_out     <<<BB*LL/8, 256, 0, stream>>>(x, total, ln_g, ln_b, oW, ob, out);
}

// Round 5
// 148.213 us; speedup vs baseline: 2.8087x; 1.1697x over previous
//
#include <hip/hip_runtime.h>
#include <math.h>

// ---------------- problem constants ----------------
#define DD   256
#define NSB  4
#define PPB  4
#define POSB 16
#define LL   2048
#define BB   2
#define NC   32         // time chunks
#define CHK  64         // LL/NC
#define NG   13         // groups: 0=cross, 1-4 banks, 5-8 pos, 9-12 ltm (4 complex slots each)
#define FS   128        // feature row stride (floats)
#define PI_F 3.14159265358979323846f

// feature row offsets (floats)
#define JK_OFF   0
#define JQ_OFF   8
#define KP_OFF   16
#define QP_OFF   48
#define LKP_OFF  80
#define GATE_OFF 112

// workspace layout (float offsets)
#define FEAT_O  0L
#define V_O     524288L                  // BB*LL*FS
#define LV_O    1572864L                 // V_O + BB*LL*DD
#define PPH_O   2621440L                 // LV_O + BB*LL*DD
#define TOT_O   2686976L                 // PPH_O + LL*32
#define CMEM_O  3735552L                 // TOT_O + BB*LL*DD ; size BB*NG*NC*8*DD = 1703936
#define WGB_O   5439488L                 // CMEM_O + 1703936
#define WS_FLOATS 5447680L               // WGB_O + BB*LL*2  (~21.8 MB)
// aliases inside the CMEM region (all dead before m_chunksum writes cmem):
#define KM_O    CMEM_O                   // g_prefix output, BB*LL*40 = 163840 floats
#define XH_O    CMEM_O                   // prep buffers, consumed by mlp_fused
#define XL_O    (CMEM_O + 524288L)
#define WTH_O   (CMEM_O + 1048576L)      // 1536*256 ushort = 196608 floats
#define WT2H_O  (CMEM_O + 1245184L)      // 3*16*256 ushort = 6144 floats; end 1251328 <= 1703936

typedef __attribute__((ext_vector_type(8))) short bf16x8;
typedef __attribute__((ext_vector_type(4))) float f32x4;

__device__ __forceinline__ float sigm(float v){ return 1.0f/(1.0f+expf(-v)); }
__device__ __forceinline__ float gelu_exact(float v){ return 0.5f*v*(1.0f+erff(v*0.70710678118654752f)); }
__device__ __forceinline__ unsigned short f2bf(float f){
    unsigned u = __float_as_uint(f);
    unsigned r = u + 0x7fffu + ((u>>16)&1u);
    return (unsigned short)(r>>16);
}
__device__ __forceinline__ float bf2f(unsigned short h){ return __uint_as_float(((unsigned)h)<<16); }

// ---------------- K0: positional phasor table ----------------
__global__ __launch_bounds__(256) void k0_posph(const float* __restrict__ pf, float* __restrict__ posph){
    int t = blockIdx.x*256 + threadIdx.x;
    if (t >= LL) return;
    #pragma unroll
    for (int j=0;j<POSB;++j){
        float ang = (((float)t * pf[j]) * 2.0f) * PI_F;
        float s,c; sincosf(ang,&s,&c);
        posph[t*32+2*j]   = c;
        posph[t*32+2*j+1] = s;
    }
}

// ---------------- P0: split x into bf16 hi/lo ----------------
__global__ __launch_bounds__(256) void prep_x(const float* __restrict__ x,
                                              unsigned short* __restrict__ xh,
                                              unsigned short* __restrict__ xl){
    long idx = (long)blockIdx.x*256 + threadIdx.x;
    float f = x[idx];
    unsigned short h = f2bf(f);
    xh[idx] = h;
    xl[idx] = f2bf(f - bf2f(h));
}

// ---------------- P1: pack + transpose first-layer weights into bf16 (hi only) ----------------
__global__ __launch_bounds__(256) void prep_w(
    const float* __restrict__ kW1, const float* __restrict__ qW1, const float* __restrict__ lW1,
    const float* __restrict__ vW,  const float* __restrict__ lvW, const float* __restrict__ gW1,
    unsigned short* __restrict__ wth)
{
    int cg = blockIdx.x;      // global col 0..1535
    int fi = threadIdx.x;
    float w = 0.f;
    if (cg < 1408){
        int m = cg >> 8;
        if (m < 5){
            const float* W = (m==0)?kW1:((m==1)?qW1:((m==2)?lW1:((m==3)?vW:lvW)));
            w = W[fi*DD + (cg & 255)];
        } else {
            w = gW1[fi*128 + (cg - 1280)];
        }
    }
    wth[(long)cg*DD + fi] = f2bf(w);
}

// ---------------- P2: pack W2^T (k/q/l second layers) into bf16 ----------------
__global__ __launch_bounds__(256) void prep_w2(
    const float* __restrict__ kW2, const float* __restrict__ qW2, const float* __restrict__ lW2,
    unsigned short* __restrict__ wt2h)
{
    int blk = blockIdx.x;          // 48: m*16+o
    int m = blk>>4, o = blk&15, k = threadIdx.x;
    const float* W2 = (m==0)?kW2:((m==1)?qW2:lW2);
    wt2h[(long)blk*DD + k] = f2bf(W2[k*16+o]);
}

// ---------------- MLP fused: MFMA GEMM + MFMA W2 epilogue ----------------
// grid = 6*128 blocks: mat = blk>>7 (0=k,1=q,2=l,3=v,4=lv,5=gate), bm = blk&127 (32-row tile)
__global__ __launch_bounds__(256) void mlp_fused(
    const unsigned short* __restrict__ xh, const unsigned short* __restrict__ xl,
    const unsigned short* __restrict__ wth, const unsigned short* __restrict__ wt2h,
    const float* __restrict__ kb1, const float* __restrict__ kb2,
    const float* __restrict__ qb1, const float* __restrict__ qb2,
    const float* __restrict__ lb1, const float* __restrict__ lb2,
    const float* __restrict__ vb,  const float* __restrict__ lvb,
    const float* __restrict__ gb1, const float* __restrict__ gW2, const float* __restrict__ gb2,
    float* __restrict__ feat, float* __restrict__ Vbuf, float* __restrict__ lvalbuf)
{
    __shared__ __align__(16) char smraw[18432];   // Hh[32][256]ush (16KB, swizzled) + ang[32][16]f32 (2KB)
    int tid = threadIdx.x, lane = tid & 63, wv = tid >> 6;
    int mat = blockIdx.x >> 7, bm = blockIdx.x & 127;
    int rowg0 = bm*32;
    int colbase = mat*256;
    int ar = lane & 15, kk = (lane>>4)*8;

    f32x4 acc[2][4];
    #pragma unroll
    for (int i=0;i<2;++i)
        #pragma unroll
        for (int j=0;j<4;++j) acc[i][j] = (f32x4){0.f,0.f,0.f,0.f};

    // ---- GEMM1: A = xh+xl (exact x), B = wh ; explicit 1-deep prefetch ----
    bf16x8 ah[2], al[2], bh[4];
    {
        int k = kk;
        #pragma unroll
        for (int i=0;i<2;++i){
            long off = (long)(rowg0 + i*16 + ar)*DD + k;
            ah[i] = *reinterpret_cast<const bf16x8*>(xh + off);
            al[i] = *reinterpret_cast<const bf16x8*>(xl + off);
        }
        #pragma unroll
        for (int j=0;j<4;++j){
            long off = (long)(colbase + wv*64 + j*16 + ar)*DD + k;
            bh[j] = *reinterpret_cast<const bf16x8*>(wth + off);
        }
    }
    #pragma unroll
    for (int ksb=0; ksb<8; ++ksb){
        bf16x8 nah[2], nal[2], nbh[4];
        if (ksb < 7){
            int k = (ksb+1)*32 + kk;
            #pragma unroll
            for (int i=0;i<2;++i){
                long off = (long)(rowg0 + i*16 + ar)*DD + k;
                nah[i] = *reinterpret_cast<const bf16x8*>(xh + off);
                nal[i] = *reinterpret_cast<const bf16x8*>(xl + off);
            }
            #pragma unroll
            for (int j=0;j<4;++j){
                long off = (long)(colbase + wv*64 + j*16 + ar)*DD + k;
                nbh[j] = *reinterpret_cast<const bf16x8*>(wth + off);
            }
        }
        #pragma unroll
        for (int i=0;i<2;++i)
            #pragma unroll
            for (int j=0;j<4;++j){
                acc[i][j] = __builtin_amdgcn_mfma_f32_16x16x32_bf16(ah[i], bh[j], acc[i][j], 0,0,0);
                acc[i][j] = __builtin_amdgcn_mfma_f32_16x16x32_bf16(al[i], bh[j], acc[i][j], 0,0,0);
            }
        if (ksb < 7){
            #pragma unroll
            for (int i=0;i<2;++i){ ah[i]=nah[i]; al[i]=nal[i]; }
            #pragma unroll
            for (int j=0;j<4;++j) bh[j]=nbh[j];
        }
    }

    // C-layout: reg r of tile(i,j): row = i*16 + (lane>>4)*4 + r, col = wv*64 + j*16 + (lane&15)
    int rl0 = (lane>>4)*4;

    if (mat < 3){
        // ---- stage gelu hidden as bf16 in swizzled LDS ----
        float (*ang)[16] = (float(*)[16])(smraw + 16384);
        const float* b1 = (mat==0)?kb1:((mat==1)?qb1:lb1);
        #pragma unroll
        for (int i=0;i<2;++i)
            #pragma unroll
            for (int j=0;j<4;++j){
                int c = wv*64 + j*16 + ar;
                #pragma unroll
                for (int r=0;r<4;++r){
                    int row = i*16 + rl0 + r;
                    float hv = gelu_exact(acc[i][j][r] + b1[c]);
                    int bo = row*512 + c*2;
                    *(unsigned short*)(smraw + (bo ^ ((row&7)<<4))) = f2bf(hv);
                }
            }
        __syncthreads();
        // ---- W2 (256->16) via MFMA: waves 0,1 each own one 16-row tile ----
        const float* b2 = (mat==0)?kb2:((mat==1)?qb2:lb2);
        int off = (mat==0)?KP_OFF:((mat==1)?QP_OFF:LKP_OFF);
        if (wv < 2){
            int arow = wv*16 + ar;
            f32x4 a2 = (f32x4){0.f,0.f,0.f,0.f};
            #pragma unroll
            for (int ksb=0; ksb<8; ++ksb){
                int k = ksb*32 + kk;
                int bo = arow*512 + k*2;
                bf16x8 af = *reinterpret_cast<const bf16x8*>(smraw + (bo ^ ((arow&7)<<4)));
                bf16x8 bf = *reinterpret_cast<const bf16x8*>(wt2h + ((long)(mat*16 + ar)*DD + k));
                a2 = __builtin_amdgcn_mfma_f32_16x16x32_bf16(af, bf, a2, 0,0,0);
            }
            int o = ar;
            #pragma unroll
            for (int r=0;r<4;++r){
                int tok = wv*16 + rl0 + r;
                float a = tanhf(a2[r] + b2[o])*PI_F;
                ang[tok][o] = a;
                float sn,cs; sincosf(a,&sn,&cs);
                long rowg = rowg0 + tok;
                feat[rowg*FS + off + 2*o]   = cs;
                feat[rowg*FS + off + 2*o+1] = sn;
            }
        }
        __syncthreads();
        if (mat<2 && tid<128){
            int tok = tid>>2, p = tid&3;
            float a = ang[tok][p]+ang[tok][4+p]+ang[tok][8+p]+ang[tok][12+p];
            float sn,cs; sincosf(a,&sn,&cs);
            int joff = (mat==0)?JK_OFF:JQ_OFF;
            long rowg = rowg0 + tok;
            feat[rowg*FS + joff + 2*p]   = cs;
            feat[rowg*FS + joff + 2*p+1] = sn;
        }
    } else if (mat < 5){
        const float* bv = (mat==3)? vb : lvb;
        float* dst = (mat==3)? Vbuf : lvalbuf;
        #pragma unroll
        for (int i=0;i<2;++i)
            #pragma unroll
            for (int j=0;j<4;++j){
                int c = wv*64 + j*16 + ar;
                #pragma unroll
                for (int r=0;r<4;++r)
                    dst[(long)(rowg0 + i*16 + rl0 + r)*DD + c] = acc[i][j][r] + bv[c];
            }
    } else {
        float (*hg)[132] = (float(*)[132])smraw;
        float (*part)[8] = (float(*)[8])(smraw + 32*132*4);
        if (wv < 2){
            #pragma unroll
            for (int i=0;i<2;++i)
                #pragma unroll
                for (int j=0;j<4;++j){
                    int c = wv*64 + j*16 + ar;
                    #pragma unroll
                    for (int r=0;r<4;++r)
                        hg[i*16 + rl0 + r][c] = gelu_exact(acc[i][j][r] + gb1[c]);
                }
        }
        __syncthreads();
        {
            int tok = tid>>3, jj = tid&7;
            float s = 0.f;
            #pragma unroll
            for (int c=0;c<16;++c) s += hg[tok][jj*16+c]*gW2[jj*16+c];
            part[tok][jj] = s;
        }
        __syncthreads();
        if (tid < 32){
            float s = gb2[0];
            #pragma unroll
            for (int j=0;j<8;++j) s += part[tid][j];
            feat[(long)(rowg0+tid)*FS + GATE_OFF] = sigm(s);
        }
    }
}

// ---------------- G-A: parallel exclusive prefix of 40 key channels ----------------
__global__ __launch_bounds__(256) void g_prefix(const float* __restrict__ feat, float* __restrict__ km){
    int b = blockIdx.x / 40, ch = blockIdx.x % 40;
    int off = (ch<8) ? (JK_OFF+ch) : (LKP_OFF + (ch-8));
    int tid = threadIdx.x;
    long rb = (long)b*LL*FS;
    float v[8]; float s = 0.f;
    #pragma unroll
    for (int u=0;u<8;++u){
        v[u] = feat[rb + (long)(tid*8+u)*FS + off];
        s += v[u];
    }
    int lane = tid & 63, w = tid >> 6;
    float xsc = s;
    #pragma unroll
    for (int o=1;o<64;o<<=1){ float y = __shfl_up(xsc,o); if (lane>=o) xsc += y; }
    __shared__ float wsum[4];
    if (lane==63) wsum[w] = xsc;
    __syncthreads();
    float woff = 0.f;
    for (int i=0;i<w;++i) woff += wsum[i];
    float run = (xsc - s) + woff;
    #pragma unroll
    for (int u=0;u<8;++u){
        km[((long)b*LL + tid*8+u)*40 + ch] = run;
        run += v[u];
    }
}

// ---------------- G-B: per-token familiarity + write gates ----------------
__global__ __launch_bounds__(256) void g_fam(
    const float* __restrict__ feat, const float* __restrict__ km,
    const float* __restrict__ ss_p, const float* __restrict__ sb_p,
    float* __restrict__ wgbuf)
{
    int t = blockIdx.x*256 + threadIdx.x;
    if (t >= BB*LL) return;
    int tc = t % LL;
    float ss = ss_p[0], sb = sb_p[0];
    long frow = (long)t*FS;
    const float* kmrow = km + (long)t*40;
    float pcb = fmaxf((float)tc, 1.0f);

    float sr=0.f, si=0.f;
    #pragma unroll
    for (int p=0;p<4;++p){
        float kr = feat[frow+JK_OFF+2*p], ki = feat[frow+JK_OFF+2*p+1];
        float kmr = kmrow[2*p], kmi = kmrow[2*p+1];
        sr += kmr*kr + kmi*ki;
        si += kmi*kr - kmr*ki;
    }
    float res = sqrtf(sr*sr+si*si);
    float fam = fminf(fmaxf(res/(pcb*2.0f),0.f),1.f);
    wgbuf[(long)t*2] = sigm(ss*(0.5f-fam)+sb);

    sr=0.f; si=0.f;
    #pragma unroll
    for (int p=0;p<16;++p){
        float kr = feat[frow+LKP_OFF+2*p], ki = feat[frow+LKP_OFF+2*p+1];
        float kmr = kmrow[8+2*p], kmi = kmrow[8+2*p+1];
        sr += kmr*kr + kmi*ki;
        si += kmi*kr - kmr*ki;
    }
    float res2 = sqrtf(sr*sr+si*si);
    float fam2 = fminf(fmaxf(res2/(pcb*4.0f),0.f),1.f);
    wgbuf[(long)t*2+1] = sigm(ss*(0.5f-fam2)+sb);
}

// ---------------- M-A: per-chunk memory sums (group-parallel) ----------------
__global__ __launch_bounds__(256) void m_chunksum(
    const float* __restrict__ feat, const float* __restrict__ posph,
    const float* __restrict__ wgbuf, const float* __restrict__ Vbuf,
    const float* __restrict__ lvalbuf, float* __restrict__ cmem)
{
    int blk = blockIdx.x;
    int b = blk/(NG*NC); int r = blk%(NG*NC); int g = r/NC, c = r%NC;
    int d = threadIdx.x;
    __shared__ float kl[CHK][8];
    __shared__ float gl[CHK];
    long frow = ((long)b*LL + c*CHK)*FS;
    for (int idx=threadIdx.x; idx<CHK*8; idx+=256){
        int t = idx>>3, j = idx&7;
        float v;
        if (g==0)       v = feat[frow + (long)t*FS + JK_OFF + j];
        else if (g<5)   v = feat[frow + (long)t*FS + KP_OFF + (g-1)*8 + j];
        else if (g<9)   v = posph[(long)(c*CHK+t)*32 + (g-5)*8 + j];
        else            v = feat[frow + (long)t*FS + LKP_OFF + (g-9)*8 + j];
        kl[t][j] = v;
    }
    for (int t=threadIdx.x; t<CHK; t+=256){
        float gf;
        if (g<5)      gf = wgbuf[((long)b*LL + c*CHK + t)*2];
        else if (g<9) gf = 1.0f;
        else          gf = wgbuf[((long)b*LL + c*CHK + t)*2 + 1];
        gl[t] = gf;
    }
    __syncthreads();
    const float* vsrc = (g>=9)? lvalbuf : Vbuf;
    long vrow = ((long)b*LL + c*CHK)*DD + d;
    float m0r=0,m0i=0,m1r=0,m1i=0,m2r=0,m2i=0,m3r=0,m3i=0;
    #pragma unroll 8
    for (int t=0;t<CHK;++t){
        float v = vsrc[vrow + (long)t*DD] * gl[t];
        m0r += kl[t][0]*v; m0i += kl[t][1]*v;
        m1r += kl[t][2]*v; m1i += kl[t][3]*v;
        m2r += kl[t][4]*v; m2i += kl[t][5]*v;
        m3r += kl[t][6]*v; m3i += kl[t][7]*v;
    }
    long ob = (long)blk*8*DD + d;
    cmem[ob+0*DD]=m0r; cmem[ob+1*DD]=m0i;
    cmem[ob+2*DD]=m1r; cmem[ob+3*DD]=m1i;
    cmem[ob+4*DD]=m2r; cmem[ob+5*DD]=m2i;
    cmem[ob+6*DD]=m3r; cmem[ob+7*DD]=m3i;
}

// ---------------- M-B: exclusive scan over chunks (register-resident) ----------------
__global__ __launch_bounds__(256) void m_scan(float* __restrict__ cmem){
    int line = blockIdx.x;            // (b*NG+g)*4 + slot
    int lb = line>>2, slot = line&3, d = threadIdx.x;
    float vr[NC], vi[NC];
    #pragma unroll
    for (int c=0;c<NC;++c){
        long a = (((long)(lb*NC + c)*4 + slot)*2)*DD + d;
        vr[c] = cmem[a]; vi[c] = cmem[a+DD];
    }
    float rr=0.f, ri=0.f;
    #pragma unroll
    for (int c=0;c<NC;++c){
        long a = (((long)(lb*NC + c)*4 + slot)*2)*DD + d;
        cmem[a] = rr; cmem[a+DD] = ri;
        rr += vr[c]; ri += vi[c];
    }
}

// ---------------- M-C: family-fused per-chunk scan + retrieval ----------------
// grid = BB*3*NC; fam 0 = cross+banks (Vbuf), 1 = pos (Vbuf), 2 = ltm (lval)
__global__ __launch_bounds__(256) void m_retrieve_fam(
    const float* __restrict__ feat, const float* __restrict__ posph,
    const float* __restrict__ wgbuf, const float* __restrict__ Vbuf,
    const float* __restrict__ lvalbuf, const float* __restrict__ cmem,
    const float* __restrict__ set_w, const float* __restrict__ pos_w,
    const float* __restrict__ ltm_w, float* __restrict__ total)
{
    int blk = blockIdx.x;
    int b = blk/(3*NC); int r = blk%(3*NC); int fam = r/NC, c = r%NC;
    int d = threadIdx.x;
    __shared__ float s_k0[CHK][16];
    __shared__ float s_kb[CHK][32];
    __shared__ float s_qb[CHK][32];
    __shared__ float s_sc[CHK][2];
    long frow = ((long)b*LL + c*CHK)*FS;

    for (int idx=threadIdx.x; idx<CHK*32; idx+=256){
        int t = idx>>5, j = idx&31;
        if (fam==0){
            s_kb[t][j] = feat[frow + (long)t*FS + KP_OFF + j];
            s_qb[t][j] = feat[frow + (long)t*FS + QP_OFF + j];
        } else if (fam==1){
            s_kb[t][j] = posph[(long)(c*CHK+t)*32 + j];
        } else {
            s_kb[t][j] = feat[frow + (long)t*FS + LKP_OFF + j];
        }
    }
    if (fam==0){
        for (int idx=threadIdx.x; idx<CHK*16; idx+=256){
            int t = idx>>4, j = idx&15;
            s_k0[t][j] = feat[frow + (long)t*FS + JK_OFF + j];
        }
    }
    for (int t=threadIdx.x; t<CHK; t+=256){
        int tc = c*CHK + t;
        float gate = feat[frow + (long)t*FS + GATE_OFF];
        if (fam==0){
            s_sc[t][0] = wgbuf[((long)b*LL+tc)*2];
            s_sc[t][1] = gate*0.2f;
        } else if (fam==1){
            s_sc[t][0] = (1.0f-gate)*sigm(pos_w[0]);
            s_sc[t][1] = 0.f;
        } else {
            s_sc[t][0] = wgbuf[((long)b*LL+tc)*2+1];
            s_sc[t][1] = sigm(ltm_w[0]) * rsqrtf((float)(tc+1)*16.0f);
        }
    }
    __syncthreads();

    long vrow = ((long)b*LL + c*CHK)*DD + d;
    float* tp = total + ((long)b*LL + c*CHK)*DD + d;

    if (fam == 0){
        float w0=expf(set_w[0]),w1=expf(set_w[1]),w2=expf(set_w[2]),w3=expf(set_w[3]);
        float den = w0+w1+w2+w3;
        float wn[4] = {w0/den, w1/den, w2/den, w3/den};
        float cr[4], ci[4], br[4][4], bi[4][4];
        #pragma unroll
        for (int s=0;s<4;++s){
            long cb0 = (((long)(b*NG+0)*NC + c)*8 + 2*s)*DD + d;
            cr[s] = cmem[cb0]; ci[s] = cmem[cb0+DD];
        }
        #pragma unroll
        for (int g=0;g<4;++g)
            #pragma unroll
            for (int s=0;s<4;++s){
                long cb = (((long)(b*NG+1+g)*NC + c)*8 + 2*s)*DD + d;
                br[g][s] = cmem[cb]; bi[g][s] = cmem[cb+DD];
            }
        #pragma unroll 4
        for (int t=0;t<CHK;++t){
            float v = Vbuf[vrow + (long)t*DD];
            float vg = v * s_sc[t][0];
            float rsc = 0.f, rb0=0.f, rb1=0.f, rb2=0.f, rb3=0.f;
            #pragma unroll
            for (int s=0;s<4;++s){
                cr[s] += s_k0[t][2*s]*vg; ci[s] += s_k0[t][2*s+1]*vg;
                rsc += cr[s]*s_k0[t][8+2*s] + ci[s]*s_k0[t][8+2*s+1];
            }
            #pragma unroll
            for (int s=0;s<4;++s){
                br[0][s] += s_kb[t][2*s]*vg;    bi[0][s] += s_kb[t][2*s+1]*vg;
                rb0 += br[0][s]*s_qb[t][2*s] + bi[0][s]*s_qb[t][2*s+1];
                br[1][s] += s_kb[t][8+2*s]*vg;  bi[1][s] += s_kb[t][8+2*s+1]*vg;
                rb1 += br[1][s]*s_qb[t][8+2*s] + bi[1][s]*s_qb[t][8+2*s+1];
                br[2][s] += s_kb[t][16+2*s]*vg; bi[2][s] += s_kb[t][16+2*s+1]*vg;
                rb2 += br[2][s]*s_qb[t][16+2*s] + bi[2][s]*s_qb[t][16+2*s+1];
                br[3][s] += s_kb[t][24+2*s]*vg; bi[3][s] += s_kb[t][24+2*s+1]*vg;
                rb3 += br[3][s]*s_qb[t][24+2*s] + bi[3][s]*s_qb[t][24+2*s+1];
            }
            float rs = s_sc[t][1]*(rsc + rb0*wn[0] + rb1*wn[1] + rb2*wn[2] + rb3*wn[3]);
            atomicAdd(tp + (long)t*DD, rs);
        }
    } else {
        const float* vsrc = (fam==2)? lvalbuf : Vbuf;
        int g0 = (fam==1)? 5 : 9;
        float mr[16], mi[16];
        #pragma unroll
        for (int g=0;g<4;++g)
            #pragma unroll
            for (int s=0;s<4;++s){
                long cb = (((long)(b*NG+g0+g)*NC + c)*8 + 2*s)*DD + d;
                mr[g*4+s] = cmem[cb]; mi[g*4+s] = cmem[cb+DD];
            }
        #pragma unroll 4
        for (int t=0;t<CHK;++t){
            float v = vsrc[vrow + (long)t*DD];
            float vg = (fam==2)? v*s_sc[t][0] : v;
            float rs = 0.f;
            #pragma unroll
            for (int j=0;j<16;++j){
                mr[j] += s_kb[t][2*j]*vg; mi[j] += s_kb[t][2*j+1]*vg;
                rs += mr[j]*s_kb[t][2*j] + mi[j]*s_kb[t][2*j+1];
            }
            float sc = (fam==2)? s_sc[t][1] : s_sc[t][0];
            atomicAdd(tp + (long)t*DD, rs*sc);
        }
    }
}

// ---------------- K4: normalize + LN + output projection + residual ----------------
__global__ __launch_bounds__(256) void k4_out(
    const float* __restrict__ x, const float* __restrict__ total,
    const float* __restrict__ ln_g, const float* __restrict__ ln_b,
    const float* __restrict__ oW,  const float* __restrict__ obv,
    float* __restrict__ out)
{
    __shared__ float tn[8][DD];
    int tid = threadIdx.x;
    long base = (long)blockIdx.x*8;
    int wave = tid>>6, lane = tid&63;
    for (int wtok=0; wtok<2; ++wtok){
        int tok = wave*2 + wtok;
        long row = base + tok;
        int tc = (int)(row % LL);
        float inv = rsqrtf((float)(tc+1)*4.0f);
        float4 tv4 = ((const float4*)(total + row*DD))[lane];
        float vals[4] = {tv4.x*inv, tv4.y*inv, tv4.z*inv, tv4.w*inv};
        float s=0.f, s2=0.f;
        #pragma unroll
        for (int k=0;k<4;++k){ s += vals[k]; s2 += vals[k]*vals[k]; }
        for (int o=1;o<64;o<<=1){ s += __shfl_xor(s,o); s2 += __shfl_xor(s2,o); }
        float mu = s/256.f, var = s2/256.f - mu*mu;
        float rstd = rsqrtf(var + 1e-5f);
        float4 w;
        w.x = (vals[0]-mu)*rstd*ln_g[lane*4+0] + ln_b[lane*4+0];
        w.y = (vals[1]-mu)*rstd*ln_g[lane*4+1] + ln_b[lane*4+1];
        w.z = (vals[2]-mu)*rstd*ln_g[lane*4+2] + ln_b[lane*4+2];
        w.w = (vals[3]-mu)*rstd*ln_g[lane*4+3] + ln_b[lane*4+3];
        ((float4*)&tn[tok][0])[lane] = w;
    }
    __syncthreads();
    float acc[8];
    #pragma unroll
    for (int tok=0;tok<8;++tok) acc[tok]=obv[tid];
    #pragma unroll 4
    for (int i=0;i<DD;++i){
        float w = oW[i*DD+tid];
        #pragma unroll
        for (int tok=0;tok<8;++tok) acc[tok] += tn[tok][i]*w;
    }
    for (int tok=0;tok<8;++tok){
        long row = base+tok;
        out[row*DD+tid] = x[row*DD+tid] + acc[tok];
    }
}

// ---------------- launch ----------------
extern "C" void kernel_launch(void* const* d_in, const int* in_sizes, int n_in,
                              void* d_out, int out_size, void* d_ws, size_t ws_size,
                              hipStream_t stream)
{
    const float* x    = (const float*)d_in[0];
    const float* kW1  = (const float*)d_in[1];
    const float* kb1  = (const float*)d_in[2];
    const float* kW2  = (const float*)d_in[3];
    const float* kb2  = (const float*)d_in[4];
    const float* qW1  = (const float*)d_in[5];
    const float* qb1  = (const float*)d_in[6];
    const float* qW2  = (const float*)d_in[7];
    const float* qb2  = (const float*)d_in[8];
    const float* vW   = (const float*)d_in[9];
    const float* vb   = (const float*)d_in[10];
    const float* ln_g = (const float*)d_in[11];
    const float* ln_b = (const float*)d_in[12];
    const float* oW   = (const float*)d_in[13];
    const float* ob   = (const float*)d_in[14];
    const float* set_w= (const float*)d_in[15];
    const float* pf   = (const float*)d_in[16];
    const float* pw   = (const float*)d_in[17];
    const float* gW1  = (const float*)d_in[18];
    const float* gb1  = (const float*)d_in[19];
    const float* gW2  = (const float*)d_in[20];
    const float* gb2  = (const float*)d_in[21];
    const float* lW1  = (const float*)d_in[22];
    const float* lb1  = (const float*)d_in[23];
    const float* lW2  = (const float*)d_in[24];
    const float* lb2  = (const float*)d_in[25];
    const float* lvW  = (const float*)d_in[26];
    const float* lvb  = (const float*)d_in[27];
    const float* ss   = (const float*)d_in[28];
    const float* sb   = (const float*)d_in[29];
    const float* lw   = (const float*)d_in[30];
    float* out = (float*)d_out;

    float* ws    = (float*)d_ws;
    float* feat  = ws + FEAT_O;
    float* Vbuf  = ws + V_O;
    float* lval  = ws + LV_O;
    float* posph = ws + PPH_O;
    float* total = ws + TOT_O;
    float* cmem  = ws + CMEM_O;
    float* km    = ws + KM_O;
    float* wgbuf = ws + WGB_O;
    unsigned short* xh   = (unsigned short*)(ws + XH_O);
    unsigned short* xl   = (unsigned short*)(ws + XL_O);
    unsigned short* wth  = (unsigned short*)(ws + WTH_O);
    unsigned short* wt2h = (unsigned short*)(ws + WT2H_O);

    (void)in_sizes; (void)n_in; (void)out_size; (void)ws_size;

    hipMemsetAsync(total, 0, (size_t)BB*LL*DD*sizeof(float), stream);

    k0_posph <<<LL/256, 256, 0, stream>>>(pf, posph);
    prep_x   <<<BB*LL*DD/256, 256, 0, stream>>>(x, xh, xl);
    prep_w   <<<1536, 256, 0, stream>>>(kW1,qW1,lW1,vW,lvW,gW1, wth);
    prep_w2  <<<48, 256, 0, stream>>>(kW2,qW2,lW2, wt2h);
    mlp_fused<<<6*128, 256, 0, stream>>>(xh,xl,wth,wt2h,
                                         kb1,kb2, qb1,qb2, lb1,lb2,
                                         vb,lvb, gb1,gW2,gb2, feat, Vbuf, lval);
    g_prefix <<<BB*40, 256, 0, stream>>>(feat, km);
    g_fam    <<<(BB*LL+255)/256, 256, 0, stream>>>(feat, km, ss, sb, wgbuf);
    m_chunksum <<<BB*NG*NC, 256, 0, stream>>>(feat, posph, wgbuf, Vbuf, lval, cmem);
    m_scan     <<<BB*NG*4, 256, 0, stream>>>(cmem);
    m_retrieve_fam <<<BB*3*NC, 256, 0, stream>>>(feat, posph, wgbuf, Vbuf, lval, cmem,
                                                 set_w, pw, lw, total);
    k4_out     <<<BB*LL/8, 256, 0, stream>>>(x, total, ln_g, ln_b, oW, ob, out);
}

// Round 6
// 140.151 us; speedup vs baseline: 2.9702x; 1.0575x over previous
//
#include <hip/hip_runtime.h>
#include <math.h>

// ---------------- problem constants ----------------
#define DD   256
#define NSB  4
#define PPB  4
#define POSB 16
#define LL   2048
#define BB   2
#define NC   32         // time chunks
#define CHK  64         // LL/NC
#define NG   13         // groups: 0=cross, 1-4 banks, 5-8 pos, 9-12 ltm (4 complex slots each)
#define FS   128        // feature row stride (floats)
#define PI_F 3.14159265358979323846f

// feature row offsets (floats)
#define JK_OFF   0
#define JQ_OFF   8
#define KP_OFF   16
#define QP_OFF   48
#define LKP_OFF  80
#define GATE_OFF 112

// workspace layout (float offsets)
#define FEAT_O  0L
#define V_O     524288L                  // BB*LL*FS
#define LV_O    1572864L                 // V_O + BB*LL*DD
#define PPH_O   2621440L                 // LV_O + BB*LL*DD
#define TOT_O   2686976L                 // PPH_O + LL*32
#define CMEM_O  3735552L                 // TOT_O + BB*LL*DD ; size BB*NG*NC*8*DD = 1703936
#define WGB_O   5439488L                 // CMEM_O + 1703936
#define WS_FLOATS 5447680L               // WGB_O + BB*LL*2  (~21.8 MB)
// aliases inside the CMEM region (all dead before m_chunksum writes cmem):
#define KM_O    CMEM_O                   // g_prefix output, BB*LL*40 = 163840 floats
#define XH_O    CMEM_O                   // prep buffers, consumed by mlp_fused
#define XL_O    (CMEM_O + 524288L)
#define WTH_O   (CMEM_O + 1048576L)      // 1536*256 ushort = 196608 floats
#define WT2H_O  (CMEM_O + 1245184L)      // 3*16*256 ushort = 6144 floats; end 1251328 <= 1703936

typedef __attribute__((ext_vector_type(8))) short bf16x8;
typedef __attribute__((ext_vector_type(4))) float f32x4;

__device__ __forceinline__ float sigm(float v){ return 1.0f/(1.0f+expf(-v)); }
__device__ __forceinline__ float gelu_exact(float v){ return 0.5f*v*(1.0f+erff(v*0.70710678118654752f)); }
__device__ __forceinline__ unsigned short f2bf(float f){
    unsigned u = __float_as_uint(f);
    unsigned r = u + 0x7fffu + ((u>>16)&1u);
    return (unsigned short)(r>>16);
}
__device__ __forceinline__ float bf2f(unsigned short h){ return __uint_as_float(((unsigned)h)<<16); }

// ---------------- K0: positional phasor table ----------------
__global__ __launch_bounds__(256) void k0_posph(const float* __restrict__ pf, float* __restrict__ posph){
    int t = blockIdx.x*256 + threadIdx.x;
    if (t >= LL) return;
    #pragma unroll
    for (int j=0;j<POSB;++j){
        float ang = (((float)t * pf[j]) * 2.0f) * PI_F;
        float s,c; sincosf(ang,&s,&c);
        posph[t*32+2*j]   = c;
        posph[t*32+2*j+1] = s;
    }
}

// ---------------- P0: split x into bf16 hi/lo ----------------
__global__ __launch_bounds__(256) void prep_x(const float* __restrict__ x,
                                              unsigned short* __restrict__ xh,
                                              unsigned short* __restrict__ xl){
    long idx = (long)blockIdx.x*256 + threadIdx.x;
    float f = x[idx];
    unsigned short h = f2bf(f);
    xh[idx] = h;
    xl[idx] = f2bf(f - bf2f(h));
}

// ---------------- P1: pack + transpose first-layer weights into bf16 (hi only) ----------------
__global__ __launch_bounds__(256) void prep_w(
    const float* __restrict__ kW1, const float* __restrict__ qW1, const float* __restrict__ lW1,
    const float* __restrict__ vW,  const float* __restrict__ lvW, const float* __restrict__ gW1,
    unsigned short* __restrict__ wth)
{
    int cg = blockIdx.x;      // global col 0..1535
    int fi = threadIdx.x;
    float w = 0.f;
    if (cg < 1408){
        int m = cg >> 8;
        if (m < 5){
            const float* W = (m==0)?kW1:((m==1)?qW1:((m==2)?lW1:((m==3)?vW:lvW)));
            w = W[fi*DD + (cg & 255)];
        } else {
            w = gW1[fi*128 + (cg - 1280)];
        }
    }
    wth[(long)cg*DD + fi] = f2bf(w);
}

// ---------------- P2: pack W2^T (k/q/l second layers) into bf16 ----------------
__global__ __launch_bounds__(256) void prep_w2(
    const float* __restrict__ kW2, const float* __restrict__ qW2, const float* __restrict__ lW2,
    unsigned short* __restrict__ wt2h)
{
    int blk = blockIdx.x;          // 48: m*16+o
    int m = blk>>4, o = blk&15, k = threadIdx.x;
    const float* W2 = (m==0)?kW2:((m==1)?qW2:lW2);
    wt2h[(long)blk*DD + k] = f2bf(W2[k*16+o]);
}

// ---------------- MLP fused: MFMA GEMM + MFMA W2 epilogue ----------------
// grid = 6*128 blocks: mat = blk>>7 (0=k,1=q,2=l,3=v,4=lv,5=gate), bm = blk&127 (32-row tile)
__global__ __launch_bounds__(256) void mlp_fused(
    const unsigned short* __restrict__ xh, const unsigned short* __restrict__ xl,
    const unsigned short* __restrict__ wth, const unsigned short* __restrict__ wt2h,
    const float* __restrict__ kb1, const float* __restrict__ kb2,
    const float* __restrict__ qb1, const float* __restrict__ qb2,
    const float* __restrict__ lb1, const float* __restrict__ lb2,
    const float* __restrict__ vb,  const float* __restrict__ lvb,
    const float* __restrict__ gb1, const float* __restrict__ gW2, const float* __restrict__ gb2,
    float* __restrict__ feat, float* __restrict__ Vbuf, float* __restrict__ lvalbuf)
{
    __shared__ __align__(16) char smraw[18432];   // Hh[32][256]ush (16KB, swizzled) + ang[32][16]f32 (2KB)
    int tid = threadIdx.x, lane = tid & 63, wv = tid >> 6;
    int mat = blockIdx.x >> 7, bm = blockIdx.x & 127;
    int rowg0 = bm*32;
    int colbase = mat*256;
    int ar = lane & 15, kk = (lane>>4)*8;

    f32x4 acc[2][4];
    #pragma unroll
    for (int i=0;i<2;++i)
        #pragma unroll
        for (int j=0;j<4;++j) acc[i][j] = (f32x4){0.f,0.f,0.f,0.f};

    // ---- GEMM1: A = xh+xl (exact x), B = wh ; explicit 1-deep prefetch ----
    bf16x8 ah[2], al[2], bh[4];
    {
        int k = kk;
        #pragma unroll
        for (int i=0;i<2;++i){
            long off = (long)(rowg0 + i*16 + ar)*DD + k;
            ah[i] = *reinterpret_cast<const bf16x8*>(xh + off);
            al[i] = *reinterpret_cast<const bf16x8*>(xl + off);
        }
        #pragma unroll
        for (int j=0;j<4;++j){
            long off = (long)(colbase + wv*64 + j*16 + ar)*DD + k;
            bh[j] = *reinterpret_cast<const bf16x8*>(wth + off);
        }
    }
    #pragma unroll
    for (int ksb=0; ksb<8; ++ksb){
        bf16x8 nah[2], nal[2], nbh[4];
        if (ksb < 7){
            int k = (ksb+1)*32 + kk;
            #pragma unroll
            for (int i=0;i<2;++i){
                long off = (long)(rowg0 + i*16 + ar)*DD + k;
                nah[i] = *reinterpret_cast<const bf16x8*>(xh + off);
                nal[i] = *reinterpret_cast<const bf16x8*>(xl + off);
            }
            #pragma unroll
            for (int j=0;j<4;++j){
                long off = (long)(colbase + wv*64 + j*16 + ar)*DD + k;
                nbh[j] = *reinterpret_cast<const bf16x8*>(wth + off);
            }
        }
        #pragma unroll
        for (int i=0;i<2;++i)
            #pragma unroll
            for (int j=0;j<4;++j){
                acc[i][j] = __builtin_amdgcn_mfma_f32_16x16x32_bf16(ah[i], bh[j], acc[i][j], 0,0,0);
                acc[i][j] = __builtin_amdgcn_mfma_f32_16x16x32_bf16(al[i], bh[j], acc[i][j], 0,0,0);
            }
        if (ksb < 7){
            #pragma unroll
            for (int i=0;i<2;++i){ ah[i]=nah[i]; al[i]=nal[i]; }
            #pragma unroll
            for (int j=0;j<4;++j) bh[j]=nbh[j];
        }
    }

    // C-layout: reg r of tile(i,j): row = i*16 + (lane>>4)*4 + r, col = wv*64 + j*16 + (lane&15)
    int rl0 = (lane>>4)*4;

    if (mat < 3){
        // ---- stage gelu hidden as bf16 in swizzled LDS ----
        float (*ang)[16] = (float(*)[16])(smraw + 16384);
        const float* b1 = (mat==0)?kb1:((mat==1)?qb1:lb1);
        #pragma unroll
        for (int i=0;i<2;++i)
            #pragma unroll
            for (int j=0;j<4;++j){
                int c = wv*64 + j*16 + ar;
                #pragma unroll
                for (int r=0;r<4;++r){
                    int row = i*16 + rl0 + r;
                    float hv = gelu_exact(acc[i][j][r] + b1[c]);
                    int bo = row*512 + c*2;
                    *(unsigned short*)(smraw + (bo ^ ((row&7)<<4))) = f2bf(hv);
                }
            }
        __syncthreads();
        // ---- W2 (256->16) via MFMA: waves 0,1 each own one 16-row tile ----
        const float* b2 = (mat==0)?kb2:((mat==1)?qb2:lb2);
        int off = (mat==0)?KP_OFF:((mat==1)?QP_OFF:LKP_OFF);
        if (wv < 2){
            int arow = wv*16 + ar;
            f32x4 a2 = (f32x4){0.f,0.f,0.f,0.f};
            #pragma unroll
            for (int ksb=0; ksb<8; ++ksb){
                int k = ksb*32 + kk;
                int bo = arow*512 + k*2;
                bf16x8 af = *reinterpret_cast<const bf16x8*>(smraw + (bo ^ ((arow&7)<<4)));
                bf16x8 bf = *reinterpret_cast<const bf16x8*>(wt2h + ((long)(mat*16 + ar)*DD + k));
                a2 = __builtin_amdgcn_mfma_f32_16x16x32_bf16(af, bf, a2, 0,0,0);
            }
            int o = ar;
            #pragma unroll
            for (int r=0;r<4;++r){
                int tok = wv*16 + rl0 + r;
                float a = tanhf(a2[r] + b2[o])*PI_F;
                ang[tok][o] = a;
                float sn,cs; sincosf(a,&sn,&cs);
                long rowg = rowg0 + tok;
                feat[rowg*FS + off + 2*o]   = cs;
                feat[rowg*FS + off + 2*o+1] = sn;
            }
        }
        __syncthreads();
        if (mat<2 && tid<128){
            int tok = tid>>2, p = tid&3;
            float a = ang[tok][p]+ang[tok][4+p]+ang[tok][8+p]+ang[tok][12+p];
            float sn,cs; sincosf(a,&sn,&cs);
            int joff = (mat==0)?JK_OFF:JQ_OFF;
            long rowg = rowg0 + tok;
            feat[rowg*FS + joff + 2*p]   = cs;
            feat[rowg*FS + joff + 2*p+1] = sn;
        }
    } else if (mat < 5){
        const float* bv = (mat==3)? vb : lvb;
        float* dst = (mat==3)? Vbuf : lvalbuf;
        #pragma unroll
        for (int i=0;i<2;++i)
            #pragma unroll
            for (int j=0;j<4;++j){
                int c = wv*64 + j*16 + ar;
                #pragma unroll
                for (int r=0;r<4;++r)
                    dst[(long)(rowg0 + i*16 + rl0 + r)*DD + c] = acc[i][j][r] + bv[c];
            }
    } else {
        float (*hg)[132] = (float(*)[132])smraw;
        float (*part)[8] = (float(*)[8])(smraw + 32*132*4);
        if (wv < 2){
            #pragma unroll
            for (int i=0;i<2;++i)
                #pragma unroll
                for (int j=0;j<4;++j){
                    int c = wv*64 + j*16 + ar;
                    #pragma unroll
                    for (int r=0;r<4;++r)
                        hg[i*16 + rl0 + r][c] = gelu_exact(acc[i][j][r] + gb1[c]);
                }
        }
        __syncthreads();
        {
            int tok = tid>>3, jj = tid&7;
            float s = 0.f;
            #pragma unroll
            for (int c=0;c<16;++c) s += hg[tok][jj*16+c]*gW2[jj*16+c];
            part[tok][jj] = s;
        }
        __syncthreads();
        if (tid < 32){
            float s = gb2[0];
            #pragma unroll
            for (int j=0;j<8;++j) s += part[tid][j];
            feat[(long)(rowg0+tid)*FS + GATE_OFF] = sigm(s);
        }
    }
}

// ---------------- G-A: parallel exclusive prefix of 40 key channels ----------------
__global__ __launch_bounds__(256) void g_prefix(const float* __restrict__ feat, float* __restrict__ km){
    int b = blockIdx.x / 40, ch = blockIdx.x % 40;
    int off = (ch<8) ? (JK_OFF+ch) : (LKP_OFF + (ch-8));
    int tid = threadIdx.x;
    long rb = (long)b*LL*FS;
    float v[8]; float s = 0.f;
    #pragma unroll
    for (int u=0;u<8;++u){
        v[u] = feat[rb + (long)(tid*8+u)*FS + off];
        s += v[u];
    }
    int lane = tid & 63, w = tid >> 6;
    float xsc = s;
    #pragma unroll
    for (int o=1;o<64;o<<=1){ float y = __shfl_up(xsc,o); if (lane>=o) xsc += y; }
    __shared__ float wsum[4];
    if (lane==63) wsum[w] = xsc;
    __syncthreads();
    float woff = 0.f;
    for (int i=0;i<w;++i) woff += wsum[i];
    float run = (xsc - s) + woff;
    #pragma unroll
    for (int u=0;u<8;++u){
        km[((long)b*LL + tid*8+u)*40 + ch] = run;
        run += v[u];
    }
}

// ---------------- G-B: per-token familiarity + write gates ----------------
__global__ __launch_bounds__(256) void g_fam(
    const float* __restrict__ feat, const float* __restrict__ km,
    const float* __restrict__ ss_p, const float* __restrict__ sb_p,
    float* __restrict__ wgbuf)
{
    int t = blockIdx.x*256 + threadIdx.x;
    if (t >= BB*LL) return;
    int tc = t % LL;
    float ss = ss_p[0], sb = sb_p[0];
    long frow = (long)t*FS;
    const float* kmrow = km + (long)t*40;
    float pcb = fmaxf((float)tc, 1.0f);

    float sr=0.f, si=0.f;
    #pragma unroll
    for (int p=0;p<4;++p){
        float kr = feat[frow+JK_OFF+2*p], ki = feat[frow+JK_OFF+2*p+1];
        float kmr = kmrow[2*p], kmi = kmrow[2*p+1];
        sr += kmr*kr + kmi*ki;
        si += kmi*kr - kmr*ki;
    }
    float res = sqrtf(sr*sr+si*si);
    float fam = fminf(fmaxf(res/(pcb*2.0f),0.f),1.f);
    wgbuf[(long)t*2] = sigm(ss*(0.5f-fam)+sb);

    sr=0.f; si=0.f;
    #pragma unroll
    for (int p=0;p<16;++p){
        float kr = feat[frow+LKP_OFF+2*p], ki = feat[frow+LKP_OFF+2*p+1];
        float kmr = kmrow[8+2*p], kmi = kmrow[8+2*p+1];
        sr += kmr*kr + kmi*ki;
        si += kmi*kr - kmr*ki;
    }
    float res2 = sqrtf(sr*sr+si*si);
    float fam2 = fminf(fmaxf(res2/(pcb*4.0f),0.f),1.f);
    wgbuf[(long)t*2+1] = sigm(ss*(0.5f-fam2)+sb);
}

// ---------------- M-A: per-chunk memory sums (128 threads, D split in 2) ----------------
__global__ __launch_bounds__(128) void m_chunksum(
    const float* __restrict__ feat, const float* __restrict__ posph,
    const float* __restrict__ wgbuf, const float* __restrict__ Vbuf,
    const float* __restrict__ lvalbuf, float* __restrict__ cmem)
{
    int blk = blockIdx.x;
    int dh = blk & 1; blk >>= 1;
    int b = blk/(NG*NC); int r = blk%(NG*NC); int g = r/NC, c = r%NC;
    int d = dh*128 + threadIdx.x;
    __shared__ __align__(16) float4 kl4[CHK][2];
    __shared__ float gl[CHK];
    long frow = ((long)b*LL + c*CHK)*FS;
    for (int idx=threadIdx.x; idx<CHK*2; idx+=128){
        int t = idx>>1, j = idx&1;
        float4 v;
        if (g==0)       v = *(const float4*)&feat[frow + (long)t*FS + JK_OFF + j*4];
        else if (g<5)   v = *(const float4*)&feat[frow + (long)t*FS + KP_OFF + (g-1)*8 + j*4];
        else if (g<9)   v = *(const float4*)&posph[(long)(c*CHK+t)*32 + (g-5)*8 + j*4];
        else            v = *(const float4*)&feat[frow + (long)t*FS + LKP_OFF + (g-9)*8 + j*4];
        kl4[t][j] = v;
    }
    for (int t=threadIdx.x; t<CHK; t+=128){
        float gf;
        if (g<5)      gf = wgbuf[((long)b*LL + c*CHK + t)*2];
        else if (g<9) gf = 1.0f;
        else          gf = wgbuf[((long)b*LL + c*CHK + t)*2 + 1];
        gl[t] = gf;
    }
    __syncthreads();
    const float* vsrc = (g>=9)? lvalbuf : Vbuf;
    long vrow = ((long)b*LL + c*CHK)*DD + d;
    float m0r=0,m0i=0,m1r=0,m1i=0,m2r=0,m2i=0,m3r=0,m3i=0;
    float vnext = vsrc[vrow];
    #pragma unroll 4
    for (int t=0;t<CHK;++t){
        float v = vnext * gl[t];
        if (t+1 < CHK) vnext = vsrc[vrow + (long)(t+1)*DD];
        float4 ka = kl4[t][0], kb = kl4[t][1];
        m0r += ka.x*v; m0i += ka.y*v;
        m1r += ka.z*v; m1i += ka.w*v;
        m2r += kb.x*v; m2i += kb.y*v;
        m3r += kb.z*v; m3i += kb.w*v;
    }
    long grp = (long)((b*NG+g)*NC + c);
    long ob = grp*8*DD + d;
    cmem[ob+0*DD]=m0r; cmem[ob+1*DD]=m0i;
    cmem[ob+2*DD]=m1r; cmem[ob+3*DD]=m1i;
    cmem[ob+4*DD]=m2r; cmem[ob+5*DD]=m2i;
    cmem[ob+6*DD]=m3r; cmem[ob+7*DD]=m3i;
}

// ---------------- M-B: exclusive scan over chunks (register-resident) ----------------
__global__ __launch_bounds__(256) void m_scan(float* __restrict__ cmem){
    int line = blockIdx.x;            // (b*NG+g)*4 + slot
    int lb = line>>2, slot = line&3, d = threadIdx.x;
    float vr[NC], vi[NC];
    #pragma unroll
    for (int c=0;c<NC;++c){
        long a = (((long)(lb*NC + c)*4 + slot)*2)*DD + d;
        vr[c] = cmem[a]; vi[c] = cmem[a+DD];
    }
    float rr=0.f, ri=0.f;
    #pragma unroll
    for (int c=0;c<NC;++c){
        long a = (((long)(lb*NC + c)*4 + slot)*2)*DD + d;
        cmem[a] = rr; cmem[a+DD] = ri;
        rr += vr[c]; ri += vi[c];
    }
}

// ---------------- M-C: family-fused per-chunk scan + retrieval (128 thr, D split) ----------------
// grid = BB*3*NC*2; fam 0 = cross+banks (Vbuf), 1 = pos (Vbuf), 2 = ltm (lval)
__global__ __launch_bounds__(128) void m_retrieve_fam(
    const float* __restrict__ feat, const float* __restrict__ posph,
    const float* __restrict__ wgbuf, const float* __restrict__ Vbuf,
    const float* __restrict__ lvalbuf, const float* __restrict__ cmem,
    const float* __restrict__ set_w, const float* __restrict__ pos_w,
    const float* __restrict__ ltm_w, float* __restrict__ total)
{
    int blk = blockIdx.x;
    int dh = blk & 1; blk >>= 1;
    int b = blk/(3*NC); int r = blk%(3*NC); int fam = r/NC, c = r%NC;
    int d = dh*128 + threadIdx.x;
    __shared__ __align__(16) float4 s_k04[CHK][4];   // fam0: jk(0,1) + jq(2,3)
    __shared__ __align__(16) float4 s_kb4[CHK][8];   // fam0: bank k; fam1: posph; fam2: lkp
    __shared__ __align__(16) float4 s_qb4[CHK][8];   // fam0 only: bank q
    __shared__ float s_sc[CHK][2];
    long frow = ((long)b*LL + c*CHK)*FS;

    for (int idx=threadIdx.x; idx<CHK*8; idx+=128){
        int t = idx>>3, j = idx&7;
        if (fam==0){
            s_kb4[t][j] = *(const float4*)&feat[frow + (long)t*FS + KP_OFF + j*4];
            s_qb4[t][j] = *(const float4*)&feat[frow + (long)t*FS + QP_OFF + j*4];
        } else if (fam==1){
            s_kb4[t][j] = *(const float4*)&posph[(long)(c*CHK+t)*32 + j*4];
        } else {
            s_kb4[t][j] = *(const float4*)&feat[frow + (long)t*FS + LKP_OFF + j*4];
        }
    }
    if (fam==0){
        for (int idx=threadIdx.x; idx<CHK*4; idx+=128){
            int t = idx>>2, j = idx&3;
            s_k04[t][j] = *(const float4*)&feat[frow + (long)t*FS + JK_OFF + j*4];
        }
    }
    for (int t=threadIdx.x; t<CHK; t+=128){
        int tc = c*CHK + t;
        float gate = feat[frow + (long)t*FS + GATE_OFF];
        if (fam==0){
            s_sc[t][0] = wgbuf[((long)b*LL+tc)*2];
            s_sc[t][1] = gate*0.2f;
        } else if (fam==1){
            s_sc[t][0] = (1.0f-gate)*sigm(pos_w[0]);
            s_sc[t][1] = 0.f;
        } else {
            s_sc[t][0] = wgbuf[((long)b*LL+tc)*2+1];
            s_sc[t][1] = sigm(ltm_w[0]) * rsqrtf((float)(tc+1)*16.0f);
        }
    }
    __syncthreads();

    long vrow = ((long)b*LL + c*CHK)*DD + d;
    float* tp = total + ((long)b*LL + c*CHK)*DD + d;

    if (fam == 0){
        float w0=expf(set_w[0]),w1=expf(set_w[1]),w2=expf(set_w[2]),w3=expf(set_w[3]);
        float den = w0+w1+w2+w3;
        float wn[4] = {w0/den, w1/den, w2/den, w3/den};
        float cr[4], ci[4], br[4][4], bi[4][4];
        #pragma unroll
        for (int s=0;s<4;++s){
            long cb0 = (((long)(b*NG+0)*NC + c)*8 + 2*s)*DD + d;
            cr[s] = cmem[cb0]; ci[s] = cmem[cb0+DD];
        }
        #pragma unroll
        for (int g=0;g<4;++g)
            #pragma unroll
            for (int s=0;s<4;++s){
                long cb = (((long)(b*NG+1+g)*NC + c)*8 + 2*s)*DD + d;
                br[g][s] = cmem[cb]; bi[g][s] = cmem[cb+DD];
            }
        float vnext = Vbuf[vrow];
        #pragma unroll 2
        for (int t=0;t<CHK;++t){
            float v = vnext;
            if (t+1 < CHK) vnext = Vbuf[vrow + (long)(t+1)*DD];
            float vg = v * s_sc[t][0];
            float4 jk0 = s_k04[t][0], jk1 = s_k04[t][1];
            float4 jq0 = s_k04[t][2], jq1 = s_k04[t][3];
            cr[0] += jk0.x*vg; ci[0] += jk0.y*vg;
            cr[1] += jk0.z*vg; ci[1] += jk0.w*vg;
            cr[2] += jk1.x*vg; ci[2] += jk1.y*vg;
            cr[3] += jk1.z*vg; ci[3] += jk1.w*vg;
            float rsc = cr[0]*jq0.x + ci[0]*jq0.y + cr[1]*jq0.z + ci[1]*jq0.w
                      + cr[2]*jq1.x + ci[2]*jq1.y + cr[3]*jq1.z + ci[3]*jq1.w;
            float rbank = 0.f;
            #pragma unroll
            for (int g=0;g<4;++g){
                float4 ka = s_kb4[t][2*g], kb = s_kb4[t][2*g+1];
                float4 qa = s_qb4[t][2*g], qb = s_qb4[t][2*g+1];
                br[g][0] += ka.x*vg; bi[g][0] += ka.y*vg;
                br[g][1] += ka.z*vg; bi[g][1] += ka.w*vg;
                br[g][2] += kb.x*vg; bi[g][2] += kb.y*vg;
                br[g][3] += kb.z*vg; bi[g][3] += kb.w*vg;
                float rg = br[g][0]*qa.x + bi[g][0]*qa.y + br[g][1]*qa.z + bi[g][1]*qa.w
                         + br[g][2]*qb.x + bi[g][2]*qb.y + br[g][3]*qb.z + bi[g][3]*qb.w;
                rbank += rg*wn[g];
            }
            float rs = s_sc[t][1]*(rsc + rbank);
            atomicAdd(tp + (long)t*DD, rs);
        }
    } else {
        const float* vsrc = (fam==2)? lvalbuf : Vbuf;
        int g0 = (fam==1)? 5 : 9;
        float mr[16], mi[16];
        #pragma unroll
        for (int g=0;g<4;++g)
            #pragma unroll
            for (int s=0;s<4;++s){
                long cb = (((long)(b*NG+g0+g)*NC + c)*8 + 2*s)*DD + d;
                mr[g*4+s] = cmem[cb]; mi[g*4+s] = cmem[cb+DD];
            }
        float vnext = vsrc[vrow];
        #pragma unroll 2
        for (int t=0;t<CHK;++t){
            float v = vnext;
            if (t+1 < CHK) vnext = vsrc[vrow + (long)(t+1)*DD];
            float vg = (fam==2)? v*s_sc[t][0] : v;
            float rs = 0.f;
            #pragma unroll
            for (int j=0;j<8;++j){
                float4 ka = s_kb4[t][j];
                mr[2*j]   += ka.x*vg; mi[2*j]   += ka.y*vg;
                rs += mr[2*j]*ka.x + mi[2*j]*ka.y;
                mr[2*j+1] += ka.z*vg; mi[2*j+1] += ka.w*vg;
                rs += mr[2*j+1]*ka.z + mi[2*j+1]*ka.w;
            }
            float sc = (fam==2)? s_sc[t][1] : s_sc[t][0];
            atomicAdd(tp + (long)t*DD, rs*sc);
        }
    }
}

// ---------------- K4: normalize + LN + output projection + residual ----------------
__global__ __launch_bounds__(256) void k4_out(
    const float* __restrict__ x, const float* __restrict__ total,
    const float* __restrict__ ln_g, const float* __restrict__ ln_b,
    const float* __restrict__ oW,  const float* __restrict__ obv,
    float* __restrict__ out)
{
    __shared__ float tn[8][DD];
    int tid = threadIdx.x;
    long base = (long)blockIdx.x*8;
    int wave = tid>>6, lane = tid&63;
    for (int wtok=0; wtok<2; ++wtok){
        int tok = wave*2 + wtok;
        long row = base + tok;
        int tc = (int)(row % LL);
        float inv = rsqrtf((float)(tc+1)*4.0f);
        float4 tv4 = ((const float4*)(total + row*DD))[lane];
        float vals[4] = {tv4.x*inv, tv4.y*inv, tv4.z*inv, tv4.w*inv};
        float s=0.f, s2=0.f;
        #pragma unroll
        for (int k=0;k<4;++k){ s += vals[k]; s2 += vals[k]*vals[k]; }
        for (int o=1;o<64;o<<=1){ s += __shfl_xor(s,o); s2 += __shfl_xor(s2,o); }
        float mu = s/256.f, var = s2/256.f - mu*mu;
        float rstd = rsqrtf(var + 1e-5f);
        float4 w;
        w.x = (vals[0]-mu)*rstd*ln_g[lane*4+0] + ln_b[lane*4+0];
        w.y = (vals[1]-mu)*rstd*ln_g[lane*4+1] + ln_b[lane*4+1];
        w.z = (vals[2]-mu)*rstd*ln_g[lane*4+2] + ln_b[lane*4+2];
        w.w = (vals[3]-mu)*rstd*ln_g[lane*4+3] + ln_b[lane*4+3];
        ((float4*)&tn[tok][0])[lane] = w;
    }
    __syncthreads();
    float acc[8];
    #pragma unroll
    for (int tok=0;tok<8;++tok) acc[tok]=obv[tid];
    #pragma unroll 4
    for (int i=0;i<DD;++i){
        float w = oW[i*DD+tid];
        #pragma unroll
        for (int tok=0;tok<8;++tok) acc[tok] += tn[tok][i]*w;
    }
    for (int tok=0;tok<8;++tok){
        long row = base+tok;
        out[row*DD+tid] = x[row*DD+tid] + acc[tok];
    }
}

// ---------------- launch ----------------
extern "C" void kernel_launch(void* const* d_in, const int* in_sizes, int n_in,
                              void* d_out, int out_size, void* d_ws, size_t ws_size,
                              hipStream_t stream)
{
    const float* x    = (const float*)d_in[0];
    const float* kW1  = (const float*)d_in[1];
    const float* kb1  = (const float*)d_in[2];
    const float* kW2  = (const float*)d_in[3];
    const float* kb2  = (const float*)d_in[4];
    const float* qW1  = (const float*)d_in[5];
    const float* qb1  = (const float*)d_in[6];
    const float* qW2  = (const float*)d_in[7];
    const float* qb2  = (const float*)d_in[8];
    const float* vW   = (const float*)d_in[9];
    const float* vb   = (const float*)d_in[10];
    const float* ln_g = (const float*)d_in[11];
    const float* ln_b = (const float*)d_in[12];
    const float* oW   = (const float*)d_in[13];
    const float* ob   = (const float*)d_in[14];
    const float* set_w= (const float*)d_in[15];
    const float* pf   = (const float*)d_in[16];
    const float* pw   = (const float*)d_in[17];
    const float* gW1  = (const float*)d_in[18];
    const float* gb1  = (const float*)d_in[19];
    const float* gW2  = (const float*)d_in[20];
    const float* gb2  = (const float*)d_in[21];
    const float* lW1  = (const float*)d_in[22];
    const float* lb1  = (const float*)d_in[23];
    const float* lW2  = (const float*)d_in[24];
    const float* lb2  = (const float*)d_in[25];
    const float* lvW  = (const float*)d_in[26];
    const float* lvb  = (const float*)d_in[27];
    const float* ss   = (const float*)d_in[28];
    const float* sb   = (const float*)d_in[29];
    const float* lw   = (const float*)d_in[30];
    float* out = (float*)d_out;

    float* ws    = (float*)d_ws;
    float* feat  = ws + FEAT_O;
    float* Vbuf  = ws + V_O;
    float* lval  = ws + LV_O;
    float* posph = ws + PPH_O;
    float* total = ws + TOT_O;
    float* cmem  = ws + CMEM_O;
    float* km    = ws + KM_O;
    float* wgbuf = ws + WGB_O;
    unsigned short* xh   = (unsigned short*)(ws + XH_O);
    unsigned short* xl   = (unsigned short*)(ws + XL_O);
    unsigned short* wth  = (unsigned short*)(ws + WTH_O);
    unsigned short* wt2h = (unsigned short*)(ws + WT2H_O);

    (void)in_sizes; (void)n_in; (void)out_size; (void)ws_size;

    hipMemsetAsync(total, 0, (size_t)BB*LL*DD*sizeof(float), stream);

    k0_posph <<<LL/256, 256, 0, stream>>>(pf, posph);
    prep_x   <<<BB*LL*DD/256, 256, 0, stream>>>(x, xh, xl);
    prep_w   <<<1536, 256, 0, stream>>>(kW1,qW1,lW1,vW,lvW,gW1, wth);
    prep_w2  <<<48, 256, 0, stream>>>(kW2,qW2,lW2, wt2h);
    mlp_fused<<<6*128, 256, 0, stream>>>(xh,xl,wth,wt2h,
                                         kb1,kb2, qb1,qb2, lb1,lb2,
                                         vb,lvb, gb1,gW2,gb2, feat, Vbuf, lval);
    g_prefix <<<BB*40, 256, 0, stream>>>(feat, km);
    g_fam    <<<(BB*LL+255)/256, 256, 0, stream>>>(feat, km, ss, sb, wgbuf);
    m_chunksum <<<BB*NG*NC*2, 128, 0, stream>>>(feat, posph, wgbuf, Vbuf, lval, cmem);
    m_scan     <<<BB*NG*4, 256, 0, stream>>>(cmem);
    m_retrieve_fam <<<BB*3*NC*2, 128, 0, stream>>>(feat, posph, wgbuf, Vbuf, lval, cmem,
                                                   set_w, pw, lw, total);
    k4_out     <<<BB*LL/8, 256, 0, stream>>>(x, total, ln_g, ln_b, oW, ob, out);
}